// Round 4
// baseline (759.033 us; speedup 1.0000x reference)
//
#include <hip/hip_runtime.h>

#define N_NODES 50000
#define N_EDGES 600000
#define N_GRAPHS 512
#define DIM 128
#define NLAYERS 4
#define NCLASSES 10
#define KPS 136   // padded LDS row stride in USHORTS (272 B, 16B-aligned)

typedef __attribute__((ext_vector_type(8))) short short8;
typedef __attribute__((ext_vector_type(4))) float f32x4;

union Frag { short8 s; uint4 u; };

// ---- fp32 <-> bf16 (RNE) helpers ----
__device__ inline unsigned short f2bf(float v) {
    union { float f; unsigned u; } c; c.f = v;
    unsigned u = c.u;
    u += 0x7FFFu + ((u >> 16) & 1u);
    return (unsigned short)(u >> 16);
}
__device__ inline float bfu_lo(unsigned u) {
    union { float f; unsigned x; } c; c.x = u << 16; return c.f;
}
__device__ inline float bfu_hi(unsigned u) {
    union { float f; unsigned x; } c; c.x = u & 0xFFFF0000u; return c.f;
}
__device__ inline void addRow(float* acc, const uint4& v) {
    acc[0] += bfu_lo(v.x); acc[1] += bfu_hi(v.x);
    acc[2] += bfu_lo(v.y); acc[3] += bfu_hi(v.y);
    acc[4] += bfu_lo(v.z); acc[5] += bfu_hi(v.z);
    acc[6] += bfu_lo(v.w); acc[7] += bfu_hi(v.w);
}

// ---------------------------------------------------------------------------
// CSR build
// ---------------------------------------------------------------------------
__global__ __launch_bounds__(256) void hist_kernel(
    const int* __restrict__ dst, int* __restrict__ deg)
{
    int e = blockIdx.x * 256 + threadIdx.x;
    if (e >= N_EDGES) return;
    atomicAdd(&deg[dst[e]], 1);
}

__global__ __launch_bounds__(256) void scan1_kernel(
    const int* __restrict__ deg, int* __restrict__ bsum)
{
    __shared__ int red[256];
    int t = threadIdx.x;
    int i4 = blockIdx.x * 256 + t;
    int s = 0;
    if (i4 < 12500) {
        int4 v = ((const int4*)deg)[i4];
        s = v.x + v.y + v.z + v.w;
    }
    red[t] = s;
    __syncthreads();
    for (int off = 128; off > 0; off >>= 1) {
        if (t < off) red[t] += red[t + off];
        __syncthreads();
    }
    if (t == 0) bsum[blockIdx.x] = red[0];
}

__global__ __launch_bounds__(64) void scan2_kernel(int* __restrict__ bsum)
{
    __shared__ int sh[64];
    int t = threadIdx.x;
    sh[t] = (t < 49) ? bsum[t] : 0;
    __syncthreads();
    if (t == 0) {
        int run = 0;
        for (int i = 0; i < 49; i++) { int v = sh[i]; sh[i] = run; run += v; }
    }
    __syncthreads();
    if (t < 49) bsum[t] = sh[t];
}

__global__ __launch_bounds__(256) void scan3_kernel(
    const int* __restrict__ deg, const int* __restrict__ bsum,
    int* __restrict__ rowptr, int* __restrict__ cursor)
{
    __shared__ int red[256];
    int t = threadIdx.x;
    int i4 = blockIdx.x * 256 + t;
    int4 v = {0, 0, 0, 0};
    if (i4 < 12500) v = ((const int4*)deg)[i4];
    int s = v.x + v.y + v.z + v.w;
    red[t] = s;
    __syncthreads();
    for (int off = 1; off < 256; off <<= 1) {
        int val = (t >= off) ? red[t - off] : 0;
        __syncthreads();
        red[t] += val;
        __syncthreads();
    }
    int run = bsum[blockIdx.x] + (t ? red[t - 1] : 0);
    if (i4 < 12500) {
        int4 rp;
        rp.x = run; run += v.x;
        rp.y = run; run += v.y;
        rp.z = run; run += v.z;
        rp.w = run; run += v.w;
        ((int4*)rowptr)[i4] = rp;
        ((int4*)cursor)[i4] = rp;
    }
    if (blockIdx.x == 0 && t == 0) rowptr[N_NODES] = N_EDGES;
}

__global__ __launch_bounds__(256) void fill_kernel(
    const int* __restrict__ src, const int* __restrict__ dst,
    int* __restrict__ cursor, int* __restrict__ csr)
{
    int e = blockIdx.x * 256 + threadIdx.x;
    if (e >= N_EDGES) return;
    int p = atomicAdd(&cursor[dst[e]], 1);
    csr[p] = src[e];
}

// ---------------------------------------------------------------------------
// Fused prep: graph bounds + x->bf16 + W pre-swizzle + stats zero.
// Block ranges: [0,196) bounds | [196,6446) xconv | [6446,6958) wconv | 6958 stats.
// ---------------------------------------------------------------------------
__global__ __launch_bounds__(256) void prep_kernel(
    const int* __restrict__ batch, int* __restrict__ gstart,
    const float* __restrict__ x, unsigned int* __restrict__ xb,
    const float* __restrict__ W1, const float* __restrict__ W2,
    unsigned short* __restrict__ whi, float* __restrict__ stats)
{
    int b = blockIdx.x;
    int t = threadIdx.x;
    if (b < 196) {
        int n = b * 256 + t;
        if (n >= N_NODES) return;
        int bb = batch[n];
        int bp = (n == 0) ? -1 : batch[n - 1];
        for (int g = bp + 1; g <= bb; g++) gstart[g] = n;
        if (n == N_NODES - 1)
            for (int g = bb + 1; g <= N_GRAPHS; g++) gstart[g] = N_NODES;
    } else if (b < 6446) {
        int idx = (b - 196) * 256 + t;
        if (idx >= N_NODES * 32) return;
        float4 v = ((const float4*)x)[idx];
        uint2 o;
        o.x = (unsigned)f2bf(v.x) | ((unsigned)f2bf(v.y) << 16);
        o.y = (unsigned)f2bf(v.z) | ((unsigned)f2bf(v.w) << 16);
        ((uint2*)xb)[idx] = o;
    } else if (b < 6958) {
        int idx = (b - 6446) * 256 + t;     // < 131072 exactly
        int f   = idx & 16383;
        int w01 = (idx >> 14) & 1;
        int l   = idx >> 15;
        int j    = f & 7;
        int lane = (f >> 3) & 63;
        int cg   = (f >> 9) & 7;
        int ks   = f >> 12;
        int k = ks * 32 + (lane >> 4) * 8 + j;
        int n = cg * 16 + (lane & 15);
        const float* W = (w01 == 0 ? W1 : W2) + (size_t)l * 16384;
        whi[idx] = f2bf(W[k * 128 + n]);
    } else {
        #pragma unroll
        for (int i = 0; i < 4; i++) stats[i * 256 + t] = 0.f;
    }
}

// ---------------------------------------------------------------------------
// FUSED GIN layer: pull-gather -> LDS (bf16) -> GEMM1 -> relu -> GEMM2 ->
// bf16 z + BN stats.  Gather uses 8-edge deep-pipelined blocks (32 uint4 in
// flight per thread) to maximize outstanding-load concurrency; the gather is
// latency x concurrency bound (R0/R1/R3 evidence: time ~ 1/(waves x depth)).
// __launch_bounds__(256,3): 3 blocks/CU (12 waves) at VGPR<=170 -> no
// residency loss vs R0, ~2x the in-flight loads.
// ---------------------------------------------------------------------------
__global__ __launch_bounds__(256, 3) void gin_layer_kernel(
    const unsigned int* __restrict__ hb,
    const int* __restrict__ rowptr, const int* __restrict__ csr,
    const float* __restrict__ epsP,
    unsigned short* __restrict__ z,
    const unsigned short* __restrict__ whi,
    const float* __restrict__ b1, const float* __restrict__ b2,
    float* __restrict__ stats)
{
    __shared__ unsigned short tpk[64 * KPS];   // 17408 B
    __shared__ float sums[1024];
    __shared__ float sqs[1024];

    const int t = threadIdx.x;
    const int lane = t & 63;
    const int w = t >> 6;
    const int wr = w & 1, wc = w >> 1;
    const int l15 = lane & 15, quad = lane >> 4;
    const int base = blockIdx.x * 64;

    // ---------------- Phase A: fused pull-aggregation ----------------
    {
        const int m = t >> 2;
        const int c = t & 3;
        const int n = base + m;
        const uint4* hb4 = (const uint4*)hb;
        float acc[32];
        #pragma unroll
        for (int i = 0; i < 32; i++) acc[i] = 0.f;
        if (n < N_NODES) {
            const float e1 = 1.0f + epsP[0];
            const uint4* self = hb4 + (size_t)n * 16 + c;
            #pragma unroll
            for (int j = 0; j < 4; j++) {
                uint4 v = self[j * 4];
                float* a = acc + j * 8;
                a[0] = e1 * bfu_lo(v.x); a[1] = e1 * bfu_hi(v.x);
                a[2] = e1 * bfu_lo(v.y); a[3] = e1 * bfu_hi(v.y);
                a[4] = e1 * bfu_lo(v.z); a[5] = e1 * bfu_hi(v.z);
                a[6] = e1 * bfu_lo(v.w); a[7] = e1 * bfu_hi(v.w);
            }
            int beg = rowptr[n], end = rowptr[n + 1];
            int e = beg;
            // ---- 8-edge deep-pipelined blocks (32 uint4 in flight) ----
            if (e + 7 < end) {
                int s0 = csr[e],     s1 = csr[e + 1], s2 = csr[e + 2], s3 = csr[e + 3];
                int s4 = csr[e + 4], s5 = csr[e + 5], s6 = csr[e + 6], s7 = csr[e + 7];
                while (true) {
                    const uint4* r0 = hb4 + (size_t)s0 * 16 + c;
                    const uint4* r1 = hb4 + (size_t)s1 * 16 + c;
                    const uint4* r2 = hb4 + (size_t)s2 * 16 + c;
                    const uint4* r3 = hb4 + (size_t)s3 * 16 + c;
                    const uint4* r4 = hb4 + (size_t)s4 * 16 + c;
                    const uint4* r5 = hb4 + (size_t)s5 * 16 + c;
                    const uint4* r6 = hb4 + (size_t)s6 * 16 + c;
                    const uint4* r7 = hb4 + (size_t)s7 * 16 + c;
                    uint4 v00 = r0[0], v01 = r0[4], v02 = r0[8], v03 = r0[12];
                    uint4 v10 = r1[0], v11 = r1[4], v12 = r1[8], v13 = r1[12];
                    uint4 v20 = r2[0], v21 = r2[4], v22 = r2[8], v23 = r2[12];
                    uint4 v30 = r3[0], v31 = r3[4], v32 = r3[8], v33 = r3[12];
                    uint4 v40 = r4[0], v41 = r4[4], v42 = r4[8], v43 = r4[12];
                    uint4 v50 = r5[0], v51 = r5[4], v52 = r5[8], v53 = r5[12];
                    uint4 v60 = r6[0], v61 = r6[4], v62 = r6[8], v63 = r6[12];
                    uint4 v70 = r7[0], v71 = r7[4], v72 = r7[8], v73 = r7[12];
                    int en = e + 8;
                    bool more = (en + 7 < end);
                    if (more) {
                        s0 = csr[en];     s1 = csr[en + 1]; s2 = csr[en + 2]; s3 = csr[en + 3];
                        s4 = csr[en + 4]; s5 = csr[en + 5]; s6 = csr[en + 6]; s7 = csr[en + 7];
                    }
                    addRow(acc + 0, v00); addRow(acc + 8, v01); addRow(acc + 16, v02); addRow(acc + 24, v03);
                    addRow(acc + 0, v10); addRow(acc + 8, v11); addRow(acc + 16, v12); addRow(acc + 24, v13);
                    addRow(acc + 0, v20); addRow(acc + 8, v21); addRow(acc + 16, v22); addRow(acc + 24, v23);
                    addRow(acc + 0, v30); addRow(acc + 8, v31); addRow(acc + 16, v32); addRow(acc + 24, v33);
                    addRow(acc + 0, v40); addRow(acc + 8, v41); addRow(acc + 16, v42); addRow(acc + 24, v43);
                    addRow(acc + 0, v50); addRow(acc + 8, v51); addRow(acc + 16, v52); addRow(acc + 24, v53);
                    addRow(acc + 0, v60); addRow(acc + 8, v61); addRow(acc + 16, v62); addRow(acc + 24, v63);
                    addRow(acc + 0, v70); addRow(acc + 8, v71); addRow(acc + 16, v72); addRow(acc + 24, v73);
                    e = en;
                    if (!more) break;
                }
            }
            // ---- one 4-edge block for the remainder ----
            if (e + 3 < end) {
                int s0 = csr[e], s1 = csr[e + 1], s2 = csr[e + 2], s3 = csr[e + 3];
                const uint4* r0 = hb4 + (size_t)s0 * 16 + c;
                const uint4* r1 = hb4 + (size_t)s1 * 16 + c;
                const uint4* r2 = hb4 + (size_t)s2 * 16 + c;
                const uint4* r3 = hb4 + (size_t)s3 * 16 + c;
                uint4 v00 = r0[0], v01 = r0[4], v02 = r0[8], v03 = r0[12];
                uint4 v10 = r1[0], v11 = r1[4], v12 = r1[8], v13 = r1[12];
                uint4 v20 = r2[0], v21 = r2[4], v22 = r2[8], v23 = r2[12];
                uint4 v30 = r3[0], v31 = r3[4], v32 = r3[8], v33 = r3[12];
                addRow(acc + 0, v00); addRow(acc + 8, v01); addRow(acc + 16, v02); addRow(acc + 24, v03);
                addRow(acc + 0, v10); addRow(acc + 8, v11); addRow(acc + 16, v12); addRow(acc + 24, v13);
                addRow(acc + 0, v20); addRow(acc + 8, v21); addRow(acc + 16, v22); addRow(acc + 24, v23);
                addRow(acc + 0, v30); addRow(acc + 8, v31); addRow(acc + 16, v32); addRow(acc + 24, v33);
                e += 4;
            }
            // ---- scalar tail ----
            for (; e < end; e++) {
                int s0 = csr[e];
                const uint4* r0 = hb4 + (size_t)s0 * 16 + c;
                uint4 a0 = r0[0], a1 = r0[4], a2 = r0[8], a3 = r0[12];
                addRow(acc + 0, a0);  addRow(acc + 8, a1);
                addRow(acc + 16, a2); addRow(acc + 24, a3);
            }
        }
        // pack bf16 (hi only) into A-layout LDS; 4 x 16B stores
        #pragma unroll
        for (int j = 0; j < 4; j++) {
            union { short8 s; unsigned short u[8]; } pk;
            #pragma unroll
            for (int i = 0; i < 8; i++) pk.u[i] = f2bf(acc[j * 8 + i]);
            *((short8*)&tpk[m * KPS + j * 32 + c * 8]) = pk.s;
        }
    }
    __syncthreads();

    f32x4 acc[2][4];
    #pragma unroll
    for (int s = 0; s < 2; s++)
        #pragma unroll
        for (int i = 0; i < 4; i++) acc[s][i] = (f32x4){0.f, 0.f, 0.f, 0.f};

    const int arow0 = (32 * wr + l15) * KPS;
    const int arow1 = arow0 + 16 * KPS;

    // ================= GEMM1: z0 @ W1 (A from LDS, bf16) =================
    #pragma unroll
    for (int kh = 0; kh < 2; kh++) {
        Frag bf[2][4];
        short8 a0[2], a1[2];
        #pragma unroll
        for (int kk = 0; kk < 2; kk++) {
            int ks = kh * 2 + kk;
            #pragma unroll
            for (int i = 0; i < 4; i++) {
                size_t woff = (size_t)(((ks * 8 + wc * 4 + i) * 64 + lane) * 8);
                bf[kk][i].s = *((const short8*)&whi[woff]);
            }
            a0[kk] = *((const short8*)&tpk[arow0 + ks * 32 + quad * 8]);
            a1[kk] = *((const short8*)&tpk[arow1 + ks * 32 + quad * 8]);
        }
        #pragma unroll
        for (int kk = 0; kk < 2; kk++) {
            #pragma unroll
            for (int i = 0; i < 4; i++) {
                acc[0][i] = __builtin_amdgcn_mfma_f32_16x16x32_bf16(a0[kk], bf[kk][i].s, acc[0][i], 0, 0, 0);
                acc[1][i] = __builtin_amdgcn_mfma_f32_16x16x32_bf16(a1[kk], bf[kk][i].s, acc[1][i], 0, 0, 0);
            }
        }
    }
    __syncthreads();

    // ---- bias + relu -> t (bf16) in LDS ----
    #pragma unroll
    for (int i = 0; i < 4; i++) {
        int col = wc * 64 + i * 16 + l15;
        float bb = b1[col];
        #pragma unroll
        for (int s = 0; s < 2; s++) {
            #pragma unroll
            for (int r = 0; r < 4; r++) {
                int m = 32 * wr + 16 * s + quad * 4 + r;
                float v = fmaxf(acc[s][i][r] + bb, 0.f);
                tpk[m * KPS + col] = f2bf(v);
            }
            acc[s][i] = (f32x4){0.f, 0.f, 0.f, 0.f};
        }
    }
    __syncthreads();

    // ================= GEMM2: t @ W2 =================
    const unsigned short* w2 = whi + 16384;
    #pragma unroll
    for (int kh = 0; kh < 2; kh++) {
        Frag bf[2][4];
        short8 a0[2], a1[2];
        #pragma unroll
        for (int kk = 0; kk < 2; kk++) {
            int ks = kh * 2 + kk;
            #pragma unroll
            for (int i = 0; i < 4; i++) {
                size_t woff = (size_t)(((ks * 8 + wc * 4 + i) * 64 + lane) * 8);
                bf[kk][i].s = *((const short8*)&w2[woff]);
            }
            a0[kk] = *((const short8*)&tpk[arow0 + ks * 32 + quad * 8]);
            a1[kk] = *((const short8*)&tpk[arow1 + ks * 32 + quad * 8]);
        }
        #pragma unroll
        for (int kk = 0; kk < 2; kk++) {
            #pragma unroll
            for (int i = 0; i < 4; i++) {
                acc[0][i] = __builtin_amdgcn_mfma_f32_16x16x32_bf16(a0[kk], bf[kk][i].s, acc[0][i], 0, 0, 0);
                acc[1][i] = __builtin_amdgcn_mfma_f32_16x16x32_bf16(a1[kk], bf[kk][i].s, acc[1][i], 0, 0, 0);
            }
        }
    }
    __syncthreads();   // tpk free for z staging

    // ---- bias; z-bf16 tile + stats partials ----
    {
        float colsum[4], colsq[4];
        #pragma unroll
        for (int i = 0; i < 4; i++) {
            int col = wc * 64 + i * 16 + l15;
            float bb = b2[col];
            float su = 0.f, q2 = 0.f;
            #pragma unroll
            for (int s = 0; s < 2; s++) {
                #pragma unroll
                for (int r = 0; r < 4; r++) {
                    int m = 32 * wr + 16 * s + quad * 4 + r;
                    int n = base + m;
                    float v = acc[s][i][r] + bb;
                    tpk[m * KPS + col] = f2bf(v);
                    if (n < N_NODES) { su += v; q2 += v * v; }
                }
            }
            colsum[i] = su; colsq[i] = q2;
        }
        #pragma unroll
        for (int i = 0; i < 4; i++) {
            sums[(w * 4 + i) * 64 + lane] = colsum[i];
            sqs [(w * 4 + i) * 64 + lane] = colsq[i];
        }
    }
    __syncthreads();

    // ---- coalesced z store (interleaved: contiguous 64B per 4-lane group) ----
    {
        int m2 = t >> 2, c2 = t & 3;
        int n2 = base + m2;
        if (n2 < N_NODES) {
            const uint4* srcp = (const uint4*)(tpk + m2 * KPS);
            uint4* dstp = (uint4*)z + (size_t)n2 * 16;
            #pragma unroll
            for (int j = 0; j < 4; j++) dstp[j * 4 + c2] = srcp[j * 4 + c2];
        }
    }
    if (t < 128) {
        int c = t;
        int wcc = c >> 6, ci = (c >> 4) & 3, cl = c & 15;
        float s = 0.f, q2 = 0.f;
        #pragma unroll
        for (int wrr = 0; wrr < 2; wrr++) {
            int ww = wcc * 2 + wrr;
            #pragma unroll
            for (int u = 0; u < 4; u++) {
                int ln = cl + u * 16;
                s  += sums[(ww * 4 + ci) * 64 + ln];
                q2 += sqs [(ww * 4 + ci) * 64 + ln];
            }
        }
        unsafeAtomicAdd(&stats[c], s);
        unsafeAtomicAdd(&stats[128 + c], q2);
    }
}

// ---------------------------------------------------------------------------
// BN apply + ReLU + write h (bf16) + pool; z packed bf16.  Layers 0..2.
// ---------------------------------------------------------------------------
__global__ __launch_bounds__(256) void bnpool_kernel(
    const unsigned int* __restrict__ z, const float* __restrict__ stats,
    const float* __restrict__ gamma, const float* __restrict__ beta,
    const int* __restrict__ gstart, unsigned int* __restrict__ hout,
    float* __restrict__ pools, int layer)
{
    __shared__ float red[8][128];
    const int g = blockIdx.x;
    const int t = threadIdx.x;
    const int q = t & 31, r = t >> 5;
    const int beg = gstart[g], end = gstart[g + 1];

    float4 s  = ((const float4*)stats)[q];
    float4 sq = ((const float4*)stats)[32 + q];
    float4 gm = ((const float4*)gamma)[q];
    float4 bt = ((const float4*)beta)[q];
    const float invN = 1.0f / (float)N_NODES;
    float m, vr;
    float4 scl, sh;
    m = s.x * invN; vr = sq.x * invN - m * m; scl.x = gm.x * rsqrtf(vr + 1e-5f); sh.x = bt.x - m * scl.x;
    m = s.y * invN; vr = sq.y * invN - m * m; scl.y = gm.y * rsqrtf(vr + 1e-5f); sh.y = bt.y - m * scl.y;
    m = s.z * invN; vr = sq.z * invN - m * m; scl.z = gm.z * rsqrtf(vr + 1e-5f); sh.z = bt.z - m * scl.z;
    m = s.w * invN; vr = sq.w * invN - m * m; scl.w = gm.w * rsqrtf(vr + 1e-5f); sh.w = bt.w - m * scl.w;

    float4 acc = {0.f, 0.f, 0.f, 0.f};
    for (int n = beg + r; n < end; n += 8) {
        uint2 zp = ((const uint2*)z)[(size_t)n * 32 + q];
        float4 hv;
        hv.x = fmaxf(bfu_lo(zp.x) * scl.x + sh.x, 0.f);
        hv.y = fmaxf(bfu_hi(zp.x) * scl.y + sh.y, 0.f);
        hv.z = fmaxf(bfu_lo(zp.y) * scl.z + sh.z, 0.f);
        hv.w = fmaxf(bfu_hi(zp.y) * scl.w + sh.w, 0.f);
        uint2 p;
        p.x = (unsigned)f2bf(hv.x) | ((unsigned)f2bf(hv.y) << 16);
        p.y = (unsigned)f2bf(hv.z) | ((unsigned)f2bf(hv.w) << 16);
        ((uint2*)hout)[(size_t)n * 32 + q] = p;
        acc.x += hv.x; acc.y += hv.y; acc.z += hv.z; acc.w += hv.w;
    }
    red[r][q * 4 + 0] = acc.x;
    red[r][q * 4 + 1] = acc.y;
    red[r][q * 4 + 2] = acc.z;
    red[r][q * 4 + 3] = acc.w;
    __syncthreads();
    if (t < 128) {
        float sm = 0.f;
        #pragma unroll
        for (int rr = 0; rr < 8; rr++) sm += red[rr][t];
        pools[(size_t)g * (DIM * NLAYERS) + (size_t)layer * DIM + t] = sm;
    }
}

// ---------------------------------------------------------------------------
// Layer-3 BN + ReLU + pool fused with the linear head (no h write needed).
// ---------------------------------------------------------------------------
__global__ __launch_bounds__(256) void bnhead_kernel(
    const unsigned int* __restrict__ z, const float* __restrict__ stats,
    const float* __restrict__ gamma, const float* __restrict__ beta,
    const int* __restrict__ gstart, const float* __restrict__ pools,
    const float* __restrict__ Wlin, const float* __restrict__ blin,
    float* __restrict__ out)
{
    __shared__ float red[8][128];
    __shared__ float pool3[128];
    const int g = blockIdx.x;
    const int t = threadIdx.x;
    const int q = t & 31, r = t >> 5;
    const int beg = gstart[g], end = gstart[g + 1];

    float4 s  = ((const float4*)stats)[q];
    float4 sq = ((const float4*)stats)[32 + q];
    float4 gm = ((const float4*)gamma)[q];
    float4 bt = ((const float4*)beta)[q];
    const float invN = 1.0f / (float)N_NODES;
    float m, vr;
    float4 scl, sh;
    m = s.x * invN; vr = sq.x * invN - m * m; scl.x = gm.x * rsqrtf(vr + 1e-5f); sh.x = bt.x - m * scl.x;
    m = s.y * invN; vr = sq.y * invN - m * m; scl.y = gm.y * rsqrtf(vr + 1e-5f); sh.y = bt.y - m * scl.y;
    m = s.z * invN; vr = sq.z * invN - m * m; scl.z = gm.z * rsqrtf(vr + 1e-5f); sh.z = bt.z - m * scl.z;
    m = s.w * invN; vr = sq.w * invN - m * m; scl.w = gm.w * rsqrtf(vr + 1e-5f); sh.w = bt.w - m * scl.w;

    float4 acc = {0.f, 0.f, 0.f, 0.f};
    for (int n = beg + r; n < end; n += 8) {
        uint2 zp = ((const uint2*)z)[(size_t)n * 32 + q];
        acc.x += fmaxf(bfu_lo(zp.x) * scl.x + sh.x, 0.f);
        acc.y += fmaxf(bfu_hi(zp.x) * scl.y + sh.y, 0.f);
        acc.z += fmaxf(bfu_lo(zp.y) * scl.z + sh.z, 0.f);
        acc.w += fmaxf(bfu_hi(zp.y) * scl.w + sh.w, 0.f);
    }
    red[r][q * 4 + 0] = acc.x;
    red[r][q * 4 + 1] = acc.y;
    red[r][q * 4 + 2] = acc.z;
    red[r][q * 4 + 3] = acc.w;
    __syncthreads();
    if (t < 128) {
        float sm = 0.f;
        #pragma unroll
        for (int rr = 0; rr < 8; rr++) sm += red[rr][t];
        pool3[t] = sm;
    }
    __syncthreads();

    if (t < 64) {
        const int lane = t;
        const float* xr = pools + (size_t)g * (DIM * NLAYERS);
        float a[NCLASSES];
        #pragma unroll
        for (int o = 0; o < NCLASSES; o++) a[o] = 0.f;
        #pragma unroll
        for (int kk = 0; kk < DIM * NLAYERS; kk += 64) {
            float xv = (kk < 3 * DIM) ? xr[kk + lane] : pool3[kk - 3 * DIM + lane];
            const float* wrow = Wlin + (size_t)(kk + lane) * NCLASSES;
            #pragma unroll
            for (int o = 0; o < NCLASSES; o++) a[o] += xv * wrow[o];
        }
        #pragma unroll
        for (int o = 0; o < NCLASSES; o++) {
            float v = a[o];
            #pragma unroll
            for (int off = 32; off > 0; off >>= 1) v += __shfl_down(v, off, 64);
            if (lane == 0) out[(size_t)g * NCLASSES + o] = v + blin[o];
        }
    }
}

// ---------------------------------------------------------------------------
extern "C" void kernel_launch(void* const* d_in, const int* in_sizes, int n_in,
                              void* d_out, int out_size, void* d_ws, size_t ws_size,
                              hipStream_t stream)
{
    const float* x     = (const float*)d_in[0];
    const int*   src   = (const int*)d_in[1];
    const int*   dst   = ((const int*)d_in[1]) + N_EDGES;
    const int*   batch = (const int*)d_in[2];
    const float* W1    = (const float*)d_in[3];
    const float* b1    = (const float*)d_in[4];
    const float* W2    = (const float*)d_in[5];
    const float* b2    = (const float*)d_in[6];
    const float* eps   = (const float*)d_in[7];
    const float* gamma = (const float*)d_in[8];
    const float* beta  = (const float*)d_in[9];
    const float* Wlin  = (const float*)d_in[10];
    const float* blin  = (const float*)d_in[11];
    float* out = (float*)d_out;

    char* ws = (char*)d_ws;
    const size_t FEATH = (size_t)N_NODES * DIM * sizeof(unsigned short); // 12.8 MB
    size_t off = 0;
    unsigned int* buf_h = (unsigned int*)(ws + off); off += FEATH;       // bf16 h
    unsigned short* buf_z = (unsigned short*)(ws + off); off += FEATH;   // bf16 z
    float* pools  = (float*)(ws + off); off += (size_t)N_GRAPHS * DIM * NLAYERS * sizeof(float);
    float* stats  = (float*)(ws + off); off += (size_t)NLAYERS * 256 * sizeof(float);
    int*   deg    = (int*)(ws + off);   off += (size_t)N_NODES * sizeof(int);      // also "cursor"
    int*   rowptr = (int*)(ws + off);   off += (size_t)(N_NODES + 1) * sizeof(int) + 12;
    int*   csr    = (int*)(ws + off);   off += (size_t)N_EDGES * sizeof(int);
    int*   gstart = (int*)(ws + off);   off += 2064;
    int*   bsum   = (int*)(ws + off);   off += 208;
    unsigned short* whi = (unsigned short*)(ws + off); off += (size_t)NLAYERS * 2 * 16384 * 2;

    hipMemsetAsync(deg, 0, (size_t)N_NODES * sizeof(int), stream);

    // ---- once per call: CSR chain + fused prep (bounds/xconv/wconv/stats) ----
    hist_kernel<<<(N_EDGES + 255) / 256, 256, 0, stream>>>(dst, deg);
    scan1_kernel<<<49, 256, 0, stream>>>(deg, bsum);
    scan2_kernel<<<1, 64, 0, stream>>>(bsum);
    scan3_kernel<<<49, 256, 0, stream>>>(deg, bsum, rowptr, deg /*cursor*/);
    fill_kernel<<<(N_EDGES + 255) / 256, 256, 0, stream>>>(src, dst, deg, csr);
    prep_kernel<<<6959, 256, 0, stream>>>(batch, gstart, x, buf_h,
                                          W1, W2, whi, stats);

    for (int l = 0; l < NLAYERS; l++) {
        gin_layer_kernel<<<(N_NODES + 63) / 64, 256, 0, stream>>>(
            buf_h, rowptr, csr, eps + l, buf_z,
            whi + (size_t)l * 32768,
            b1 + (size_t)l * DIM, b2 + (size_t)l * DIM,
            stats + (size_t)l * 256);
        if (l < NLAYERS - 1) {
            bnpool_kernel<<<N_GRAPHS, 256, 0, stream>>>(
                (const unsigned int*)buf_z, stats + (size_t)l * 256,
                gamma + (size_t)l * DIM, beta + (size_t)l * DIM,
                gstart, buf_h, pools, l);
        }
    }
    bnhead_kernel<<<N_GRAPHS, 256, 0, stream>>>(
        (const unsigned int*)buf_z, stats + (size_t)(NLAYERS - 1) * 256,
        gamma + (size_t)(NLAYERS - 1) * DIM, beta + (size_t)(NLAYERS - 1) * DIM,
        gstart, pools, Wlin, blin, out);
}

// Round 5
// 547.499 us; speedup vs baseline: 1.3864x; 1.3864x over previous
//
#include <hip/hip_runtime.h>

#define N_NODES 50000
#define N_EDGES 600000
#define N_GRAPHS 512
#define DIM 128
#define NLAYERS 4
#define NCLASSES 10
#define KPS 136   // padded LDS row stride in USHORTS (272 B, 16B-aligned)

typedef __attribute__((ext_vector_type(8))) short short8;
typedef __attribute__((ext_vector_type(4))) float f32x4;

union Frag { short8 s; uint4 u; };

// ---- fp32 <-> bf16 (RNE) helpers ----
__device__ inline unsigned short f2bf(float v) {
    union { float f; unsigned u; } c; c.f = v;
    unsigned u = c.u;
    u += 0x7FFFu + ((u >> 16) & 1u);
    return (unsigned short)(u >> 16);
}
__device__ inline float bfu_lo(unsigned u) {
    union { float f; unsigned x; } c; c.x = u << 16; return c.f;
}
__device__ inline float bfu_hi(unsigned u) {
    union { float f; unsigned x; } c; c.x = u & 0xFFFF0000u; return c.f;
}
__device__ inline void addRow(float* acc, const uint4& v) {
    acc[0] += bfu_lo(v.x); acc[1] += bfu_hi(v.x);
    acc[2] += bfu_lo(v.y); acc[3] += bfu_hi(v.y);
    acc[4] += bfu_lo(v.z); acc[5] += bfu_hi(v.z);
    acc[6] += bfu_lo(v.w); acc[7] += bfu_hi(v.w);
}
// BN+ReLU each of the 8 bf16 elements of v with packed coeffs cf[k] =
// (bf16(scl)<<16)|bf16(sh), writing h[k] = max(z*scl+sh, 0).
__device__ inline void bnRow(float* h, const uint4& v, const unsigned* cf) {
    h[0] = fmaxf(bfu_lo(v.x) * bfu_hi(cf[0]) + bfu_lo(cf[0]), 0.f);
    h[1] = fmaxf(bfu_hi(v.x) * bfu_hi(cf[1]) + bfu_lo(cf[1]), 0.f);
    h[2] = fmaxf(bfu_lo(v.y) * bfu_hi(cf[2]) + bfu_lo(cf[2]), 0.f);
    h[3] = fmaxf(bfu_hi(v.y) * bfu_hi(cf[3]) + bfu_lo(cf[3]), 0.f);
    h[4] = fmaxf(bfu_lo(v.z) * bfu_hi(cf[4]) + bfu_lo(cf[4]), 0.f);
    h[5] = fmaxf(bfu_hi(v.z) * bfu_hi(cf[5]) + bfu_lo(cf[5]), 0.f);
    h[6] = fmaxf(bfu_lo(v.w) * bfu_hi(cf[6]) + bfu_lo(cf[6]), 0.f);
    h[7] = fmaxf(bfu_hi(v.w) * bfu_hi(cf[7]) + bfu_lo(cf[7]), 0.f);
}
template<int MODE>
__device__ inline void addRowM(float* a, const uint4& v, const unsigned* cf) {
    if constexpr (MODE) {
        float h[8]; bnRow(h, v, cf);
        a[0] += h[0]; a[1] += h[1]; a[2] += h[2]; a[3] += h[3];
        a[4] += h[4]; a[5] += h[5]; a[6] += h[6]; a[7] += h[7];
    } else {
        addRow(a, v);
    }
}

// ---------------------------------------------------------------------------
// CSR build
// ---------------------------------------------------------------------------
__global__ __launch_bounds__(256) void hist_kernel(
    const int* __restrict__ dst, int* __restrict__ deg)
{
    int e = blockIdx.x * 256 + threadIdx.x;
    if (e >= N_EDGES) return;
    atomicAdd(&deg[dst[e]], 1);
}

__global__ __launch_bounds__(256) void scan1_kernel(
    const int* __restrict__ deg, int* __restrict__ bsum)
{
    __shared__ int red[256];
    int t = threadIdx.x;
    int i4 = blockIdx.x * 256 + t;
    int s = 0;
    if (i4 < 12500) {
        int4 v = ((const int4*)deg)[i4];
        s = v.x + v.y + v.z + v.w;
    }
    red[t] = s;
    __syncthreads();
    for (int off = 128; off > 0; off >>= 1) {
        if (t < off) red[t] += red[t + off];
        __syncthreads();
    }
    if (t == 0) bsum[blockIdx.x] = red[0];
}

__global__ __launch_bounds__(64) void scan2_kernel(int* __restrict__ bsum)
{
    __shared__ int sh[64];
    int t = threadIdx.x;
    sh[t] = (t < 49) ? bsum[t] : 0;
    __syncthreads();
    if (t == 0) {
        int run = 0;
        for (int i = 0; i < 49; i++) { int v = sh[i]; sh[i] = run; run += v; }
    }
    __syncthreads();
    if (t < 49) bsum[t] = sh[t];
}

__global__ __launch_bounds__(256) void scan3_kernel(
    const int* __restrict__ deg, const int* __restrict__ bsum,
    int* __restrict__ rowptr, int* __restrict__ cursor)
{
    __shared__ int red[256];
    int t = threadIdx.x;
    int i4 = blockIdx.x * 256 + t;
    int4 v = {0, 0, 0, 0};
    if (i4 < 12500) v = ((const int4*)deg)[i4];
    int s = v.x + v.y + v.z + v.w;
    red[t] = s;
    __syncthreads();
    for (int off = 1; off < 256; off <<= 1) {
        int val = (t >= off) ? red[t - off] : 0;
        __syncthreads();
        red[t] += val;
        __syncthreads();
    }
    int run = bsum[blockIdx.x] + (t ? red[t - 1] : 0);
    if (i4 < 12500) {
        int4 rp;
        rp.x = run; run += v.x;
        rp.y = run; run += v.y;
        rp.z = run; run += v.z;
        rp.w = run; run += v.w;
        ((int4*)rowptr)[i4] = rp;
        ((int4*)cursor)[i4] = rp;
    }
    if (blockIdx.x == 0 && t == 0) rowptr[N_NODES] = N_EDGES;
}

__global__ __launch_bounds__(256) void fill_kernel(
    const int* __restrict__ src, const int* __restrict__ dst,
    int* __restrict__ cursor, int* __restrict__ csr)
{
    int e = blockIdx.x * 256 + threadIdx.x;
    if (e >= N_EDGES) return;
    int p = atomicAdd(&cursor[dst[e]], 1);
    csr[p] = src[e];
}

// ---------------------------------------------------------------------------
// Fused prep: graph bounds + x->bf16 + W pre-swizzle + stats zero + pools zero.
// Block ranges: [0,196) bounds | [196,6446) xconv | [6446,6958) wconv |
// 6958 stats | [6959,7983) pools.
// ---------------------------------------------------------------------------
__global__ __launch_bounds__(256) void prep_kernel(
    const int* __restrict__ batch, int* __restrict__ gstart,
    const float* __restrict__ x, unsigned int* __restrict__ xb,
    const float* __restrict__ W1, const float* __restrict__ W2,
    unsigned short* __restrict__ whi, float* __restrict__ stats,
    float* __restrict__ pools)
{
    int b = blockIdx.x;
    int t = threadIdx.x;
    if (b < 196) {
        int n = b * 256 + t;
        if (n >= N_NODES) return;
        int bb = batch[n];
        int bp = (n == 0) ? -1 : batch[n - 1];
        for (int g = bp + 1; g <= bb; g++) gstart[g] = n;
        if (n == N_NODES - 1)
            for (int g = bb + 1; g <= N_GRAPHS; g++) gstart[g] = N_NODES;
    } else if (b < 6446) {
        int idx = (b - 196) * 256 + t;
        if (idx >= N_NODES * 32) return;
        float4 v = ((const float4*)x)[idx];
        uint2 o;
        o.x = (unsigned)f2bf(v.x) | ((unsigned)f2bf(v.y) << 16);
        o.y = (unsigned)f2bf(v.z) | ((unsigned)f2bf(v.w) << 16);
        ((uint2*)xb)[idx] = o;
    } else if (b < 6958) {
        int idx = (b - 6446) * 256 + t;     // < 131072 exactly
        int f   = idx & 16383;
        int w01 = (idx >> 14) & 1;
        int l   = idx >> 15;
        int j    = f & 7;
        int lane = (f >> 3) & 63;
        int cg   = (f >> 9) & 7;
        int ks   = f >> 12;
        int k = ks * 32 + (lane >> 4) * 8 + j;
        int n = cg * 16 + (lane & 15);
        const float* W = (w01 == 0 ? W1 : W2) + (size_t)l * 16384;
        whi[idx] = f2bf(W[k * 128 + n]);
    } else if (b == 6958) {
        #pragma unroll
        for (int i = 0; i < 4; i++) stats[i * 256 + t] = 0.f;
    } else {
        int idx = (b - 6959) * 256 + t;     // < 262144 exactly
        pools[idx] = 0.f;
    }
}

// ---------------------------------------------------------------------------
// FUSED GIN layer.  MODE 0 (layer 0): input = bf16 x, plain gather.
// MODE 1 (layers 1..3): input = raw bf16 z of the previous layer; BN+ReLU
// applied ON READ (packed bf16 scale/shift in 32 regs/thread), and the
// previous layer's global_add_pool is accumulated from the BN'd SELF rows
// (each node's h row is computed exactly once here) via an LDS segmented
// reduction + a few hundred global atomics per block.  This removes the
// bnpool pass entirely (3 kernels + 25.6 MB/layer h round-trip).
// Gather core = round-0 ladder (4 edges x 4 uint4 in flight), which sits at
// the per-CU line-fill roofline (~13 cy/line).  NO min-waves clamp (R1/R4).
// ---------------------------------------------------------------------------
template<int MODE>
__global__ __launch_bounds__(256) void gin_layer_kernel(
    const unsigned int* __restrict__ zin,
    const int* __restrict__ rowptr, const int* __restrict__ csr,
    const float* __restrict__ epsP,
    unsigned short* __restrict__ zout,
    const unsigned short* __restrict__ whi,
    const float* __restrict__ b1, const float* __restrict__ b2,
    float* __restrict__ stats,
    const float* __restrict__ statsP,
    const float* __restrict__ gammaP, const float* __restrict__ betaP,
    const int* __restrict__ batch, float* __restrict__ pools, int lm1)
{
    __shared__ unsigned short tpk[64 * KPS];   // 17408 B
    __shared__ float sums[1024];
    __shared__ float sqs[1024];
    __shared__ float pool_lds[8][128];         // 4096 B (MODE1)

    const int t = threadIdx.x;
    const int lane = t & 63;
    const int w = t >> 6;
    const int wr = w & 1, wc = w >> 1;
    const int l15 = lane & 15, quad = lane >> 4;
    const int base = blockIdx.x * 64;

    if constexpr (MODE) {
        ((float*)pool_lds)[t]       = 0.f;
        ((float*)pool_lds)[256 + t] = 0.f;
        ((float*)pool_lds)[512 + t] = 0.f;
        ((float*)pool_lds)[768 + t] = 0.f;
        __syncthreads();
    }

    // ---------------- Phase A: fused pull-aggregation ----------------
    {
        const int m = t >> 2;
        const int c = t & 3;
        const int n = base + m;
        const uint4* hb4 = (const uint4*)zin;
        float acc[32];
        unsigned cf[32];                      // packed (scl,sh) per owned col
        #pragma unroll
        for (int i = 0; i < 32; i++) acc[i] = 0.f;
        if constexpr (MODE) {
            const float invN = 1.0f / (float)N_NODES;
            #pragma unroll
            for (int j = 0; j < 4; j++) {
                int cb = 32 * j + 8 * c;
                #pragma unroll
                for (int k = 0; k < 8; k++) {
                    float mean = statsP[cb + k] * invN;
                    float var  = statsP[128 + cb + k] * invN - mean * mean;
                    float scl  = gammaP[cb + k] * rsqrtf(var + 1e-5f);
                    float shv  = betaP[cb + k] - mean * scl;
                    cf[j * 8 + k] = ((unsigned)f2bf(scl) << 16) | (unsigned)f2bf(shv);
                }
            }
        }
        if (n < N_NODES) {
            const float e1 = 1.0f + epsP[0];
            const uint4* self = hb4 + (size_t)n * 16 + c;
            if constexpr (MODE) {
                int g = batch[n];
                int slot = g - batch[base];
                #pragma unroll
                for (int j = 0; j < 4; j++) {
                    uint4 v = self[j * 4];
                    float h[8];
                    bnRow(h, v, cf + j * 8);
                    int cb = 32 * j + 8 * c;
                    if (slot < 8) {
                        #pragma unroll
                        for (int k = 0; k < 8; k++)
                            atomicAdd(&pool_lds[slot][cb + k], h[k]);
                    } else {
                        #pragma unroll
                        for (int k = 0; k < 8; k++)
                            unsafeAtomicAdd(&pools[(size_t)g * (DIM * NLAYERS)
                                                   + (size_t)lm1 * DIM + cb + k], h[k]);
                    }
                    float* a = acc + j * 8;
                    #pragma unroll
                    for (int k = 0; k < 8; k++) a[k] = e1 * h[k];
                }
            } else {
                #pragma unroll
                for (int j = 0; j < 4; j++) {
                    uint4 v = self[j * 4];
                    float* a = acc + j * 8;
                    a[0] = e1 * bfu_lo(v.x); a[1] = e1 * bfu_hi(v.x);
                    a[2] = e1 * bfu_lo(v.y); a[3] = e1 * bfu_hi(v.y);
                    a[4] = e1 * bfu_lo(v.z); a[5] = e1 * bfu_hi(v.z);
                    a[6] = e1 * bfu_lo(v.w); a[7] = e1 * bfu_hi(v.w);
                }
            }
            int beg = rowptr[n], end = rowptr[n + 1];
            int e = beg;
            if (e + 3 < end) {
                int s0 = csr[e], s1 = csr[e + 1], s2 = csr[e + 2], s3 = csr[e + 3];
                while (true) {
                    const uint4* r0 = hb4 + (size_t)s0 * 16 + c;
                    const uint4* r1 = hb4 + (size_t)s1 * 16 + c;
                    const uint4* r2 = hb4 + (size_t)s2 * 16 + c;
                    const uint4* r3 = hb4 + (size_t)s3 * 16 + c;
                    uint4 v00 = r0[0], v01 = r0[4], v02 = r0[8], v03 = r0[12];
                    uint4 v10 = r1[0], v11 = r1[4], v12 = r1[8], v13 = r1[12];
                    uint4 v20 = r2[0], v21 = r2[4], v22 = r2[8], v23 = r2[12];
                    uint4 v30 = r3[0], v31 = r3[4], v32 = r3[8], v33 = r3[12];
                    int en = e + 4;
                    bool more = (en + 3 < end);
                    if (more) {
                        s0 = csr[en]; s1 = csr[en + 1];
                        s2 = csr[en + 2]; s3 = csr[en + 3];
                    }
                    addRowM<MODE>(acc + 0, v00, cf + 0);  addRowM<MODE>(acc + 8, v01, cf + 8);
                    addRowM<MODE>(acc + 16, v02, cf + 16); addRowM<MODE>(acc + 24, v03, cf + 24);
                    addRowM<MODE>(acc + 0, v10, cf + 0);  addRowM<MODE>(acc + 8, v11, cf + 8);
                    addRowM<MODE>(acc + 16, v12, cf + 16); addRowM<MODE>(acc + 24, v13, cf + 24);
                    addRowM<MODE>(acc + 0, v20, cf + 0);  addRowM<MODE>(acc + 8, v21, cf + 8);
                    addRowM<MODE>(acc + 16, v22, cf + 16); addRowM<MODE>(acc + 24, v23, cf + 24);
                    addRowM<MODE>(acc + 0, v30, cf + 0);  addRowM<MODE>(acc + 8, v31, cf + 8);
                    addRowM<MODE>(acc + 16, v32, cf + 16); addRowM<MODE>(acc + 24, v33, cf + 24);
                    e = en;
                    if (!more) break;
                }
            }
            for (; e < end; e++) {
                int s0 = csr[e];
                const uint4* r0 = hb4 + (size_t)s0 * 16 + c;
                uint4 a0 = r0[0], a1 = r0[4], a2 = r0[8], a3 = r0[12];
                addRowM<MODE>(acc + 0, a0, cf + 0);   addRowM<MODE>(acc + 8, a1, cf + 8);
                addRowM<MODE>(acc + 16, a2, cf + 16); addRowM<MODE>(acc + 24, a3, cf + 24);
            }
        }
        // pack bf16 into A-layout LDS; 4 x 16B stores
        #pragma unroll
        for (int j = 0; j < 4; j++) {
            union { short8 s; unsigned short u[8]; } pk;
            #pragma unroll
            for (int i = 0; i < 8; i++) pk.u[i] = f2bf(acc[j * 8 + i]);
            *((short8*)&tpk[m * KPS + j * 32 + c * 8]) = pk.s;
        }
    }
    __syncthreads();

    f32x4 acc[2][4];
    #pragma unroll
    for (int s = 0; s < 2; s++)
        #pragma unroll
        for (int i = 0; i < 4; i++) acc[s][i] = (f32x4){0.f, 0.f, 0.f, 0.f};

    const int arow0 = (32 * wr + l15) * KPS;
    const int arow1 = arow0 + 16 * KPS;

    // ================= GEMM1: z0 @ W1 (A from LDS, bf16) =================
    #pragma unroll
    for (int kh = 0; kh < 2; kh++) {
        Frag bf[2][4];
        short8 a0[2], a1[2];
        #pragma unroll
        for (int kk = 0; kk < 2; kk++) {
            int ks = kh * 2 + kk;
            #pragma unroll
            for (int i = 0; i < 4; i++) {
                size_t woff = (size_t)(((ks * 8 + wc * 4 + i) * 64 + lane) * 8);
                bf[kk][i].s = *((const short8*)&whi[woff]);
            }
            a0[kk] = *((const short8*)&tpk[arow0 + ks * 32 + quad * 8]);
            a1[kk] = *((const short8*)&tpk[arow1 + ks * 32 + quad * 8]);
        }
        #pragma unroll
        for (int kk = 0; kk < 2; kk++) {
            #pragma unroll
            for (int i = 0; i < 4; i++) {
                acc[0][i] = __builtin_amdgcn_mfma_f32_16x16x32_bf16(a0[kk], bf[kk][i].s, acc[0][i], 0, 0, 0);
                acc[1][i] = __builtin_amdgcn_mfma_f32_16x16x32_bf16(a1[kk], bf[kk][i].s, acc[1][i], 0, 0, 0);
            }
        }
    }
    __syncthreads();

    // ---- bias + relu -> t (bf16) in LDS ----
    #pragma unroll
    for (int i = 0; i < 4; i++) {
        int col = wc * 64 + i * 16 + l15;
        float bb = b1[col];
        #pragma unroll
        for (int s = 0; s < 2; s++) {
            #pragma unroll
            for (int r = 0; r < 4; r++) {
                int m = 32 * wr + 16 * s + quad * 4 + r;
                float v = fmaxf(acc[s][i][r] + bb, 0.f);
                tpk[m * KPS + col] = f2bf(v);
            }
            acc[s][i] = (f32x4){0.f, 0.f, 0.f, 0.f};
        }
    }
    __syncthreads();

    // ================= GEMM2: t @ W2 =================
    const unsigned short* w2 = whi + 16384;
    #pragma unroll
    for (int kh = 0; kh < 2; kh++) {
        Frag bf[2][4];
        short8 a0[2], a1[2];
        #pragma unroll
        for (int kk = 0; kk < 2; kk++) {
            int ks = kh * 2 + kk;
            #pragma unroll
            for (int i = 0; i < 4; i++) {
                size_t woff = (size_t)(((ks * 8 + wc * 4 + i) * 64 + lane) * 8);
                bf[kk][i].s = *((const short8*)&w2[woff]);
            }
            a0[kk] = *((const short8*)&tpk[arow0 + ks * 32 + quad * 8]);
            a1[kk] = *((const short8*)&tpk[arow1 + ks * 32 + quad * 8]);
        }
        #pragma unroll
        for (int kk = 0; kk < 2; kk++) {
            #pragma unroll
            for (int i = 0; i < 4; i++) {
                acc[0][i] = __builtin_amdgcn_mfma_f32_16x16x32_bf16(a0[kk], bf[kk][i].s, acc[0][i], 0, 0, 0);
                acc[1][i] = __builtin_amdgcn_mfma_f32_16x16x32_bf16(a1[kk], bf[kk][i].s, acc[1][i], 0, 0, 0);
            }
        }
    }
    __syncthreads();   // tpk free for z staging

    // ---- bias; z-bf16 tile + stats partials ----
    {
        float colsum[4], colsq[4];
        #pragma unroll
        for (int i = 0; i < 4; i++) {
            int col = wc * 64 + i * 16 + l15;
            float bb = b2[col];
            float su = 0.f, q2 = 0.f;
            #pragma unroll
            for (int s = 0; s < 2; s++) {
                #pragma unroll
                for (int r = 0; r < 4; r++) {
                    int m = 32 * wr + 16 * s + quad * 4 + r;
                    int n = base + m;
                    float v = acc[s][i][r] + bb;
                    tpk[m * KPS + col] = f2bf(v);
                    if (n < N_NODES) { su += v; q2 += v * v; }
                }
            }
            colsum[i] = su; colsq[i] = q2;
        }
        #pragma unroll
        for (int i = 0; i < 4; i++) {
            sums[(w * 4 + i) * 64 + lane] = colsum[i];
            sqs [(w * 4 + i) * 64 + lane] = colsq[i];
        }
    }
    __syncthreads();

    // ---- coalesced z store (interleaved: contiguous 64B per 4-lane group) ----
    {
        int m2 = t >> 2, c2 = t & 3;
        int n2 = base + m2;
        if (n2 < N_NODES) {
            const uint4* srcp = (const uint4*)(tpk + m2 * KPS);
            uint4* dstp = (uint4*)zout + (size_t)n2 * 16;
            #pragma unroll
            for (int j = 0; j < 4; j++) dstp[j * 4 + c2] = srcp[j * 4 + c2];
        }
    }
    if (t < 128) {
        int c = t;
        int wcc = c >> 6, ci = (c >> 4) & 3, cl = c & 15;
        float s = 0.f, q2 = 0.f;
        #pragma unroll
        for (int wrr = 0; wrr < 2; wrr++) {
            int ww = wcc * 2 + wrr;
            #pragma unroll
            for (int u = 0; u < 4; u++) {
                int ln = cl + u * 16;
                s  += sums[(ww * 4 + ci) * 64 + ln];
                q2 += sqs [(ww * 4 + ci) * 64 + ln];
            }
        }
        unsafeAtomicAdd(&stats[c], s);
        unsafeAtomicAdd(&stats[128 + c], q2);
    }
    // ---- pool(l-1) flush: LDS graph slots -> global atomics ----
    if constexpr (MODE) {
        if (t < 128) {
            int g0 = batch[base];
            #pragma unroll
            for (int s = 0; s < 8; s++) {
                int g = g0 + s;
                float v = pool_lds[s][t];
                if (g < N_GRAPHS && v != 0.f)
                    unsafeAtomicAdd(&pools[(size_t)g * (DIM * NLAYERS)
                                           + (size_t)lm1 * DIM + t], v);
            }
        }
    }
}

// ---------------------------------------------------------------------------
// Layer-3 BN + ReLU + pool fused with the linear head (no h write needed).
// ---------------------------------------------------------------------------
__global__ __launch_bounds__(256) void bnhead_kernel(
    const unsigned int* __restrict__ z, const float* __restrict__ stats,
    const float* __restrict__ gamma, const float* __restrict__ beta,
    const int* __restrict__ gstart, const float* __restrict__ pools,
    const float* __restrict__ Wlin, const float* __restrict__ blin,
    float* __restrict__ out)
{
    __shared__ float red[8][128];
    __shared__ float pool3[128];
    const int g = blockIdx.x;
    const int t = threadIdx.x;
    const int q = t & 31, r = t >> 5;
    const int beg = gstart[g], end = gstart[g + 1];

    float4 s  = ((const float4*)stats)[q];
    float4 sq = ((const float4*)stats)[32 + q];
    float4 gm = ((const float4*)gamma)[q];
    float4 bt = ((const float4*)beta)[q];
    const float invN = 1.0f / (float)N_NODES;
    float m, vr;
    float4 scl, sh;
    m = s.x * invN; vr = sq.x * invN - m * m; scl.x = gm.x * rsqrtf(vr + 1e-5f); sh.x = bt.x - m * scl.x;
    m = s.y * invN; vr = sq.y * invN - m * m; scl.y = gm.y * rsqrtf(vr + 1e-5f); sh.y = bt.y - m * scl.y;
    m = s.z * invN; vr = sq.z * invN - m * m; scl.z = gm.z * rsqrtf(vr + 1e-5f); sh.z = bt.z - m * scl.z;
    m = s.w * invN; vr = sq.w * invN - m * m; scl.w = gm.w * rsqrtf(vr + 1e-5f); sh.w = bt.w - m * scl.w;

    float4 acc = {0.f, 0.f, 0.f, 0.f};
    for (int n = beg + r; n < end; n += 8) {
        uint2 zp = ((const uint2*)z)[(size_t)n * 32 + q];
        acc.x += fmaxf(bfu_lo(zp.x) * scl.x + sh.x, 0.f);
        acc.y += fmaxf(bfu_hi(zp.x) * scl.y + sh.y, 0.f);
        acc.z += fmaxf(bfu_lo(zp.y) * scl.z + sh.z, 0.f);
        acc.w += fmaxf(bfu_hi(zp.y) * scl.w + sh.w, 0.f);
    }
    red[r][q * 4 + 0] = acc.x;
    red[r][q * 4 + 1] = acc.y;
    red[r][q * 4 + 2] = acc.z;
    red[r][q * 4 + 3] = acc.w;
    __syncthreads();
    if (t < 128) {
        float sm = 0.f;
        #pragma unroll
        for (int rr = 0; rr < 8; rr++) sm += red[rr][t];
        pool3[t] = sm;
    }
    __syncthreads();

    if (t < 64) {
        const int lane = t;
        const float* xr = pools + (size_t)g * (DIM * NLAYERS);
        float a[NCLASSES];
        #pragma unroll
        for (int o = 0; o < NCLASSES; o++) a[o] = 0.f;
        #pragma unroll
        for (int kk = 0; kk < DIM * NLAYERS; kk += 64) {
            float xv = (kk < 3 * DIM) ? xr[kk + lane] : pool3[kk - 3 * DIM + lane];
            const float* wrow = Wlin + (size_t)(kk + lane) * NCLASSES;
            #pragma unroll
            for (int o = 0; o < NCLASSES; o++) a[o] += xv * wrow[o];
        }
        #pragma unroll
        for (int o = 0; o < NCLASSES; o++) {
            float v = a[o];
            #pragma unroll
            for (int off = 32; off > 0; off >>= 1) v += __shfl_down(v, off, 64);
            if (lane == 0) out[(size_t)g * NCLASSES + o] = v + blin[o];
        }
    }
}

// ---------------------------------------------------------------------------
extern "C" void kernel_launch(void* const* d_in, const int* in_sizes, int n_in,
                              void* d_out, int out_size, void* d_ws, size_t ws_size,
                              hipStream_t stream)
{
    const float* x     = (const float*)d_in[0];
    const int*   src   = (const int*)d_in[1];
    const int*   dst   = ((const int*)d_in[1]) + N_EDGES;
    const int*   batch = (const int*)d_in[2];
    const float* W1    = (const float*)d_in[3];
    const float* b1    = (const float*)d_in[4];
    const float* W2    = (const float*)d_in[5];
    const float* b2    = (const float*)d_in[6];
    const float* eps   = (const float*)d_in[7];
    const float* gamma = (const float*)d_in[8];
    const float* beta  = (const float*)d_in[9];
    const float* Wlin  = (const float*)d_in[10];
    const float* blin  = (const float*)d_in[11];
    float* out = (float*)d_out;

    char* ws = (char*)d_ws;
    const size_t FEATH = (size_t)N_NODES * DIM * sizeof(unsigned short); // 12.8 MB
    size_t off = 0;
    unsigned int* xb = (unsigned int*)(ws + off); off += FEATH;          // bf16 x
    unsigned short* zb0 = (unsigned short*)(ws + off); off += FEATH;     // bf16 z ping
    unsigned short* zb1 = (unsigned short*)(ws + off); off += FEATH;     // bf16 z pong
    float* pools  = (float*)(ws + off); off += (size_t)N_GRAPHS * DIM * NLAYERS * sizeof(float);
    float* stats  = (float*)(ws + off); off += (size_t)NLAYERS * 256 * sizeof(float);
    int*   deg    = (int*)(ws + off);   off += (size_t)N_NODES * sizeof(int);      // also "cursor"
    int*   rowptr = (int*)(ws + off);   off += (size_t)(N_NODES + 1) * sizeof(int) + 12;
    int*   csr    = (int*)(ws + off);   off += (size_t)N_EDGES * sizeof(int);
    int*   gstart = (int*)(ws + off);   off += 2064;
    int*   bsum   = (int*)(ws + off);   off += 208;
    unsigned short* whi = (unsigned short*)(ws + off); off += (size_t)NLAYERS * 2 * 16384 * 2;

    unsigned short* zping[2] = { zb0, zb1 };

    hipMemsetAsync(deg, 0, (size_t)N_NODES * sizeof(int), stream);

    // ---- once per call: CSR chain + fused prep ----
    hist_kernel<<<(N_EDGES + 255) / 256, 256, 0, stream>>>(dst, deg);
    scan1_kernel<<<49, 256, 0, stream>>>(deg, bsum);
    scan2_kernel<<<1, 64, 0, stream>>>(bsum);
    scan3_kernel<<<49, 256, 0, stream>>>(deg, bsum, rowptr, deg /*cursor*/);
    fill_kernel<<<(N_EDGES + 255) / 256, 256, 0, stream>>>(src, dst, deg, csr);
    prep_kernel<<<7983, 256, 0, stream>>>(batch, gstart, x, xb,
                                          W1, W2, whi, stats, pools);

    const int GINGRID = (N_NODES + 63) / 64;
    // layer 0: plain gather of x
    gin_layer_kernel<0><<<GINGRID, 256, 0, stream>>>(
        xb, rowptr, csr, eps + 0, zping[0],
        whi, b1, b2, stats,
        nullptr, nullptr, nullptr, batch, pools, 0);
    // layers 1..3: BN-on-read of z_{l-1} + pool(l-1)
    for (int l = 1; l < NLAYERS; l++) {
        gin_layer_kernel<1><<<GINGRID, 256, 0, stream>>>(
            (const unsigned int*)zping[(l - 1) & 1], rowptr, csr, eps + l, zping[l & 1],
            whi + (size_t)l * 32768,
            b1 + (size_t)l * DIM, b2 + (size_t)l * DIM,
            stats + (size_t)l * 256,
            stats + (size_t)(l - 1) * 256,
            gamma + (size_t)(l - 1) * DIM, beta + (size_t)(l - 1) * DIM,
            batch, pools, l - 1);
    }
    bnhead_kernel<<<N_GRAPHS, 256, 0, stream>>>(
        (const unsigned int*)zping[1], stats + (size_t)(NLAYERS - 1) * 256,
        gamma + (size_t)(NLAYERS - 1) * DIM, beta + (size_t)(NLAYERS - 1) * DIM,
        gstart, pools, Wlin, blin, out);
}

// Round 13
// 399.723 us; speedup vs baseline: 1.8989x; 1.3697x over previous
//
#include <hip/hip_runtime.h>

#define N_NODES 50000
#define N_EDGES 600000
#define N_GRAPHS 512
#define DIM 128
#define NLAYERS 4
#define NCLASSES 10
#define KPS 136      // padded LDS row stride in USHORTS (272 B, 16B-aligned)
#define NBUCK 4
#define BUCKSZ 12500 // source-node bucket size: 12500 rows * 256 B = 3.2 MB (< 4 MB L2/XCD)

typedef __attribute__((ext_vector_type(8))) short short8;
typedef __attribute__((ext_vector_type(4))) float f32x4;

union Frag { short8 s; uint4 u; };

// ---- fp32 <-> bf16 (RNE) helpers ----
__device__ inline unsigned short f2bf(float v) {
    union { float f; unsigned u; } c; c.f = v;
    unsigned u = c.u;
    u += 0x7FFFu + ((u >> 16) & 1u);
    return (unsigned short)(u >> 16);
}
__device__ inline float bfu_lo(unsigned u) {
    union { float f; unsigned x; } c; c.x = u << 16; return c.f;
}
__device__ inline float bfu_hi(unsigned u) {
    union { float f; unsigned x; } c; c.x = u & 0xFFFF0000u; return c.f;
}
__device__ inline void addRow(float* acc, const uint4& v) {
    acc[0] += bfu_lo(v.x); acc[1] += bfu_hi(v.x);
    acc[2] += bfu_lo(v.y); acc[3] += bfu_hi(v.y);
    acc[4] += bfu_lo(v.z); acc[5] += bfu_hi(v.z);
    acc[6] += bfu_lo(v.w); acc[7] += bfu_hi(v.w);
}

// ---------------------------------------------------------------------------
// Bucketed CSR build: per-node, per-source-bucket degree histogram so each
// adjacency list is stored bucket-0..3 contiguously.  Blocks then sweep
// buckets in near-lockstep -> instantaneous gather working set ~3.2 MB,
// L2-resident per XCD (latency ~halves; gather is latency x MLP bound).
// deg4/rowptr4 are indexed [node*4 + bucket]; 200000 cursors total.
// ---------------------------------------------------------------------------
__global__ __launch_bounds__(256) void hist_kernel(
    const int* __restrict__ src, const int* __restrict__ dst,
    int* __restrict__ deg4)
{
    int e = blockIdx.x * 256 + threadIdx.x;
    if (e >= N_EDGES) return;
    int s = src[e];
    atomicAdd(&deg4[dst[e] * 4 + s / BUCKSZ], 1);
}

__global__ __launch_bounds__(256) void scan1_kernel(
    const int* __restrict__ deg4, int* __restrict__ bsum)
{
    __shared__ int red[256];
    int t = threadIdx.x;
    int i4 = blockIdx.x * 256 + t;
    int s = 0;
    if (i4 < 50000) {
        int4 v = ((const int4*)deg4)[i4];
        s = v.x + v.y + v.z + v.w;
    }
    red[t] = s;
    __syncthreads();
    for (int off = 128; off > 0; off >>= 1) {
        if (t < off) red[t] += red[t + off];
        __syncthreads();
    }
    if (t == 0) bsum[blockIdx.x] = red[0];
}

__global__ __launch_bounds__(256) void scan2_kernel(int* __restrict__ bsum)
{
    __shared__ int sh[256];
    int t = threadIdx.x;
    sh[t] = (t < 196) ? bsum[t] : 0;
    __syncthreads();
    if (t == 0) {
        int run = 0;
        for (int i = 0; i < 196; i++) { int v = sh[i]; sh[i] = run; run += v; }
    }
    __syncthreads();
    if (t < 196) bsum[t] = sh[t];
}

__global__ __launch_bounds__(256) void scan3_kernel(
    const int* __restrict__ deg4, const int* __restrict__ bsum,
    int* __restrict__ rowptr4, int* __restrict__ cursor4)
{
    __shared__ int red[256];
    int t = threadIdx.x;
    int i4 = blockIdx.x * 256 + t;
    int4 v = {0, 0, 0, 0};
    if (i4 < 50000) v = ((const int4*)deg4)[i4];
    int s = v.x + v.y + v.z + v.w;
    red[t] = s;
    __syncthreads();
    for (int off = 1; off < 256; off <<= 1) {
        int val = (t >= off) ? red[t - off] : 0;
        __syncthreads();
        red[t] += val;
        __syncthreads();
    }
    int run = bsum[blockIdx.x] + (t ? red[t - 1] : 0);
    if (i4 < 50000) {
        int4 rp;
        rp.x = run; run += v.x;
        rp.y = run; run += v.y;
        rp.z = run; run += v.z;
        rp.w = run; run += v.w;
        ((int4*)rowptr4)[i4] = rp;
        ((int4*)cursor4)[i4] = rp;
    }
    if (blockIdx.x == 0 && t == 0) rowptr4[4 * N_NODES] = N_EDGES;
}

__global__ __launch_bounds__(256) void fill_kernel(
    const int* __restrict__ src, const int* __restrict__ dst,
    int* __restrict__ cursor4, int* __restrict__ csr)
{
    int e = blockIdx.x * 256 + threadIdx.x;
    if (e >= N_EDGES) return;
    int s = src[e];
    int p = atomicAdd(&cursor4[dst[e] * 4 + s / BUCKSZ], 1);
    csr[p] = s;
}

// ---------------------------------------------------------------------------
// Fused prep: graph bounds + x->bf16 + W pre-swizzle + stats zero.
// Block ranges: [0,196) bounds | [196,6446) xconv | [6446,6958) wconv | 6958 stats.
// ---------------------------------------------------------------------------
__global__ __launch_bounds__(256) void prep_kernel(
    const int* __restrict__ batch, int* __restrict__ gstart,
    const float* __restrict__ x, unsigned int* __restrict__ xb,
    const float* __restrict__ W1, const float* __restrict__ W2,
    unsigned short* __restrict__ whi, float* __restrict__ stats)
{
    int b = blockIdx.x;
    int t = threadIdx.x;
    if (b < 196) {
        int n = b * 256 + t;
        if (n >= N_NODES) return;
        int bb = batch[n];
        int bp = (n == 0) ? -1 : batch[n - 1];
        for (int g = bp + 1; g <= bb; g++) gstart[g] = n;
        if (n == N_NODES - 1)
            for (int g = bb + 1; g <= N_GRAPHS; g++) gstart[g] = N_NODES;
    } else if (b < 6446) {
        int idx = (b - 196) * 256 + t;
        if (idx >= N_NODES * 32) return;
        float4 v = ((const float4*)x)[idx];
        uint2 o;
        o.x = (unsigned)f2bf(v.x) | ((unsigned)f2bf(v.y) << 16);
        o.y = (unsigned)f2bf(v.z) | ((unsigned)f2bf(v.w) << 16);
        ((uint2*)xb)[idx] = o;
    } else if (b < 6958) {
        int idx = (b - 6446) * 256 + t;     // < 131072 exactly
        int f   = idx & 16383;
        int w01 = (idx >> 14) & 1;
        int l   = idx >> 15;
        int j    = f & 7;
        int lane = (f >> 3) & 63;
        int cg   = (f >> 9) & 7;
        int ks   = f >> 12;
        int k = ks * 32 + (lane >> 4) * 8 + j;
        int n = cg * 16 + (lane & 15);
        const float* W = (w01 == 0 ? W1 : W2) + (size_t)l * 16384;
        whi[idx] = f2bf(W[k * 128 + n]);
    } else {
        #pragma unroll
        for (int i = 0; i < 4; i++) stats[i * 256 + t] = 0.f;
    }
}

// ---------------------------------------------------------------------------
// FUSED GIN layer (exact round-0 gather ladder; only rowptr indexing differs:
// node n's adjacency = [rowptr4[4n], rowptr4[4n+4]), stored bucket-ordered).
// pull-gather -> LDS (bf16) -> GEMM1 -> relu -> GEMM2 -> bf16 z + BN stats.
// ---------------------------------------------------------------------------
__global__ __launch_bounds__(256) void gin_layer_kernel(
    const unsigned int* __restrict__ hb,
    const int* __restrict__ rowptr4, const int* __restrict__ csr,
    const float* __restrict__ epsP,
    unsigned short* __restrict__ z,
    const unsigned short* __restrict__ whi,
    const float* __restrict__ b1, const float* __restrict__ b2,
    float* __restrict__ stats)
{
    __shared__ unsigned short tpk[64 * KPS];   // 17408 B
    __shared__ float sums[1024];
    __shared__ float sqs[1024];

    const int t = threadIdx.x;
    const int lane = t & 63;
    const int w = t >> 6;
    const int wr = w & 1, wc = w >> 1;
    const int l15 = lane & 15, quad = lane >> 4;
    const int base = blockIdx.x * 64;

    // ---------------- Phase A: fused pull-aggregation ----------------
    {
        const int m = t >> 2;
        const int c = t & 3;
        const int n = base + m;
        const uint4* hb4 = (const uint4*)hb;
        float acc[32];
        #pragma unroll
        for (int i = 0; i < 32; i++) acc[i] = 0.f;
        if (n < N_NODES) {
            const float e1 = 1.0f + epsP[0];
            const uint4* self = hb4 + (size_t)n * 16 + c;
            #pragma unroll
            for (int j = 0; j < 4; j++) {
                uint4 v = self[j * 4];
                float* a = acc + j * 8;
                a[0] = e1 * bfu_lo(v.x); a[1] = e1 * bfu_hi(v.x);
                a[2] = e1 * bfu_lo(v.y); a[3] = e1 * bfu_hi(v.y);
                a[4] = e1 * bfu_lo(v.z); a[5] = e1 * bfu_hi(v.z);
                a[6] = e1 * bfu_lo(v.w); a[7] = e1 * bfu_hi(v.w);
            }
            int beg = rowptr4[n * 4], end = rowptr4[n * 4 + 4];
            int e = beg;
            if (e + 3 < end) {
                int s0 = csr[e], s1 = csr[e + 1], s2 = csr[e + 2], s3 = csr[e + 3];
                while (true) {
                    const uint4* r0 = hb4 + (size_t)s0 * 16 + c;
                    const uint4* r1 = hb4 + (size_t)s1 * 16 + c;
                    const uint4* r2 = hb4 + (size_t)s2 * 16 + c;
                    const uint4* r3 = hb4 + (size_t)s3 * 16 + c;
                    uint4 v00 = r0[0], v01 = r0[4], v02 = r0[8], v03 = r0[12];
                    uint4 v10 = r1[0], v11 = r1[4], v12 = r1[8], v13 = r1[12];
                    uint4 v20 = r2[0], v21 = r2[4], v22 = r2[8], v23 = r2[12];
                    uint4 v30 = r3[0], v31 = r3[4], v32 = r3[8], v33 = r3[12];
                    int en = e + 4;
                    bool more = (en + 3 < end);
                    if (more) {
                        s0 = csr[en]; s1 = csr[en + 1];
                        s2 = csr[en + 2]; s3 = csr[en + 3];
                    }
                    addRow(acc + 0, v00); addRow(acc + 8, v01); addRow(acc + 16, v02); addRow(acc + 24, v03);
                    addRow(acc + 0, v10); addRow(acc + 8, v11); addRow(acc + 16, v12); addRow(acc + 24, v13);
                    addRow(acc + 0, v20); addRow(acc + 8, v21); addRow(acc + 16, v22); addRow(acc + 24, v23);
                    addRow(acc + 0, v30); addRow(acc + 8, v31); addRow(acc + 16, v32); addRow(acc + 24, v33);
                    e = en;
                    if (!more) break;
                }
            }
            for (; e < end; e++) {
                int s0 = csr[e];
                const uint4* r0 = hb4 + (size_t)s0 * 16 + c;
                uint4 a0 = r0[0], a1 = r0[4], a2 = r0[8], a3 = r0[12];
                addRow(acc + 0, a0);  addRow(acc + 8, a1);
                addRow(acc + 16, a2); addRow(acc + 24, a3);
            }
        }
        // pack bf16 (hi only) into A-layout LDS; 4 x 16B stores
        #pragma unroll
        for (int j = 0; j < 4; j++) {
            union { short8 s; unsigned short u[8]; } pk;
            #pragma unroll
            for (int i = 0; i < 8; i++) pk.u[i] = f2bf(acc[j * 8 + i]);
            *((short8*)&tpk[m * KPS + j * 32 + c * 8]) = pk.s;
        }
    }
    __syncthreads();

    f32x4 acc[2][4];
    #pragma unroll
    for (int s = 0; s < 2; s++)
        #pragma unroll
        for (int i = 0; i < 4; i++) acc[s][i] = (f32x4){0.f, 0.f, 0.f, 0.f};

    const int arow0 = (32 * wr + l15) * KPS;
    const int arow1 = arow0 + 16 * KPS;

    // ================= GEMM1: z0 @ W1 (A from LDS, bf16) =================
    #pragma unroll
    for (int kh = 0; kh < 2; kh++) {
        Frag bf[2][4];
        short8 a0[2], a1[2];
        #pragma unroll
        for (int kk = 0; kk < 2; kk++) {
            int ks = kh * 2 + kk;
            #pragma unroll
            for (int i = 0; i < 4; i++) {
                size_t woff = (size_t)(((ks * 8 + wc * 4 + i) * 64 + lane) * 8);
                bf[kk][i].s = *((const short8*)&whi[woff]);
            }
            a0[kk] = *((const short8*)&tpk[arow0 + ks * 32 + quad * 8]);
            a1[kk] = *((const short8*)&tpk[arow1 + ks * 32 + quad * 8]);
        }
        #pragma unroll
        for (int kk = 0; kk < 2; kk++) {
            #pragma unroll
            for (int i = 0; i < 4; i++) {
                acc[0][i] = __builtin_amdgcn_mfma_f32_16x16x32_bf16(a0[kk], bf[kk][i].s, acc[0][i], 0, 0, 0);
                acc[1][i] = __builtin_amdgcn_mfma_f32_16x16x32_bf16(a1[kk], bf[kk][i].s, acc[1][i], 0, 0, 0);
            }
        }
    }
    __syncthreads();

    // ---- bias + relu -> t (bf16) in LDS ----
    #pragma unroll
    for (int i = 0; i < 4; i++) {
        int col = wc * 64 + i * 16 + l15;
        float bb = b1[col];
        #pragma unroll
        for (int s = 0; s < 2; s++) {
            #pragma unroll
            for (int r = 0; r < 4; r++) {
                int m = 32 * wr + 16 * s + quad * 4 + r;
                float v = fmaxf(acc[s][i][r] + bb, 0.f);
                tpk[m * KPS + col] = f2bf(v);
            }
            acc[s][i] = (f32x4){0.f, 0.f, 0.f, 0.f};
        }
    }
    __syncthreads();

    // ================= GEMM2: t @ W2 =================
    const unsigned short* w2 = whi + 16384;
    #pragma unroll
    for (int kh = 0; kh < 2; kh++) {
        Frag bf[2][4];
        short8 a0[2], a1[2];
        #pragma unroll
        for (int kk = 0; kk < 2; kk++) {
            int ks = kh * 2 + kk;
            #pragma unroll
            for (int i = 0; i < 4; i++) {
                size_t woff = (size_t)(((ks * 8 + wc * 4 + i) * 64 + lane) * 8);
                bf[kk][i].s = *((const short8*)&w2[woff]);
            }
            a0[kk] = *((const short8*)&tpk[arow0 + ks * 32 + quad * 8]);
            a1[kk] = *((const short8*)&tpk[arow1 + ks * 32 + quad * 8]);
        }
        #pragma unroll
        for (int kk = 0; kk < 2; kk++) {
            #pragma unroll
            for (int i = 0; i < 4; i++) {
                acc[0][i] = __builtin_amdgcn_mfma_f32_16x16x32_bf16(a0[kk], bf[kk][i].s, acc[0][i], 0, 0, 0);
                acc[1][i] = __builtin_amdgcn_mfma_f32_16x16x32_bf16(a1[kk], bf[kk][i].s, acc[1][i], 0, 0, 0);
            }
        }
    }
    __syncthreads();   // tpk free for z staging

    // ---- bias; z-bf16 tile + stats partials ----
    {
        float colsum[4], colsq[4];
        #pragma unroll
        for (int i = 0; i < 4; i++) {
            int col = wc * 64 + i * 16 + l15;
            float bb = b2[col];
            float su = 0.f, q2 = 0.f;
            #pragma unroll
            for (int s = 0; s < 2; s++) {
                #pragma unroll
                for (int r = 0; r < 4; r++) {
                    int m = 32 * wr + 16 * s + quad * 4 + r;
                    int n = base + m;
                    float v = acc[s][i][r] + bb;
                    tpk[m * KPS + col] = f2bf(v);
                    if (n < N_NODES) { su += v; q2 += v * v; }
                }
            }
            colsum[i] = su; colsq[i] = q2;
        }
        #pragma unroll
        for (int i = 0; i < 4; i++) {
            sums[(w * 4 + i) * 64 + lane] = colsum[i];
            sqs [(w * 4 + i) * 64 + lane] = colsq[i];
        }
    }
    __syncthreads();

    // ---- coalesced z store (interleaved: contiguous 64B per 4-lane group) ----
    {
        int m2 = t >> 2, c2 = t & 3;
        int n2 = base + m2;
        if (n2 < N_NODES) {
            const uint4* srcp = (const uint4*)(tpk + m2 * KPS);
            uint4* dstp = (uint4*)z + (size_t)n2 * 16;
            #pragma unroll
            for (int j = 0; j < 4; j++) dstp[j * 4 + c2] = srcp[j * 4 + c2];
        }
    }
    if (t < 128) {
        int c = t;
        int wcc = c >> 6, ci = (c >> 4) & 3, cl = c & 15;
        float s = 0.f, q2 = 0.f;
        #pragma unroll
        for (int wrr = 0; wrr < 2; wrr++) {
            int ww = wcc * 2 + wrr;
            #pragma unroll
            for (int u = 0; u < 4; u++) {
                int ln = cl + u * 16;
                s  += sums[(ww * 4 + ci) * 64 + ln];
                q2 += sqs [(ww * 4 + ci) * 64 + ln];
            }
        }
        unsafeAtomicAdd(&stats[c], s);
        unsafeAtomicAdd(&stats[128 + c], q2);
    }
}

// ---------------------------------------------------------------------------
// BN apply + ReLU + write h (bf16) + pool; z packed bf16.  Layers 0..2.
// ---------------------------------------------------------------------------
__global__ __launch_bounds__(256) void bnpool_kernel(
    const unsigned int* __restrict__ z, const float* __restrict__ stats,
    const float* __restrict__ gamma, const float* __restrict__ beta,
    const int* __restrict__ gstart, unsigned int* __restrict__ hout,
    float* __restrict__ pools, int layer)
{
    __shared__ float red[8][128];
    const int g = blockIdx.x;
    const int t = threadIdx.x;
    const int q = t & 31, r = t >> 5;
    const int beg = gstart[g], end = gstart[g + 1];

    float4 s  = ((const float4*)stats)[q];
    float4 sq = ((const float4*)stats)[32 + q];
    float4 gm = ((const float4*)gamma)[q];
    float4 bt = ((const float4*)beta)[q];
    const float invN = 1.0f / (float)N_NODES;
    float m, vr;
    float4 scl, sh;
    m = s.x * invN; vr = sq.x * invN - m * m; scl.x = gm.x * rsqrtf(vr + 1e-5f); sh.x = bt.x - m * scl.x;
    m = s.y * invN; vr = sq.y * invN - m * m; scl.y = gm.y * rsqrtf(vr + 1e-5f); sh.y = bt.y - m * scl.y;
    m = s.z * invN; vr = sq.z * invN - m * m; scl.z = gm.z * rsqrtf(vr + 1e-5f); sh.z = bt.z - m * scl.z;
    m = s.w * invN; vr = sq.w * invN - m * m; scl.w = gm.w * rsqrtf(vr + 1e-5f); sh.w = bt.w - m * scl.w;

    float4 acc = {0.f, 0.f, 0.f, 0.f};
    for (int n = beg + r; n < end; n += 8) {
        uint2 zp = ((const uint2*)z)[(size_t)n * 32 + q];
        float4 hv;
        hv.x = fmaxf(bfu_lo(zp.x) * scl.x + sh.x, 0.f);
        hv.y = fmaxf(bfu_hi(zp.x) * scl.y + sh.y, 0.f);
        hv.z = fmaxf(bfu_lo(zp.y) * scl.z + sh.z, 0.f);
        hv.w = fmaxf(bfu_hi(zp.y) * scl.w + sh.w, 0.f);
        uint2 p;
        p.x = (unsigned)f2bf(hv.x) | ((unsigned)f2bf(hv.y) << 16);
        p.y = (unsigned)f2bf(hv.z) | ((unsigned)f2bf(hv.w) << 16);
        ((uint2*)hout)[(size_t)n * 32 + q] = p;
        acc.x += hv.x; acc.y += hv.y; acc.z += hv.z; acc.w += hv.w;
    }
    red[r][q * 4 + 0] = acc.x;
    red[r][q * 4 + 1] = acc.y;
    red[r][q * 4 + 2] = acc.z;
    red[r][q * 4 + 3] = acc.w;
    __syncthreads();
    if (t < 128) {
        float sm = 0.f;
        #pragma unroll
        for (int rr = 0; rr < 8; rr++) sm += red[rr][t];
        pools[(size_t)g * (DIM * NLAYERS) + (size_t)layer * DIM + t] = sm;
    }
}

// ---------------------------------------------------------------------------
// Layer-3 BN + ReLU + pool fused with the linear head (no h write needed).
// ---------------------------------------------------------------------------
__global__ __launch_bounds__(256) void bnhead_kernel(
    const unsigned int* __restrict__ z, const float* __restrict__ stats,
    const float* __restrict__ gamma, const float* __restrict__ beta,
    const int* __restrict__ gstart, const float* __restrict__ pools,
    const float* __restrict__ Wlin, const float* __restrict__ blin,
    float* __restrict__ out)
{
    __shared__ float red[8][128];
    __shared__ float pool3[128];
    const int g = blockIdx.x;
    const int t = threadIdx.x;
    const int q = t & 31, r = t >> 5;
    const int beg = gstart[g], end = gstart[g + 1];

    float4 s  = ((const float4*)stats)[q];
    float4 sq = ((const float4*)stats)[32 + q];
    float4 gm = ((const float4*)gamma)[q];
    float4 bt = ((const float4*)beta)[q];
    const float invN = 1.0f / (float)N_NODES;
    float m, vr;
    float4 scl, sh;
    m = s.x * invN; vr = sq.x * invN - m * m; scl.x = gm.x * rsqrtf(vr + 1e-5f); sh.x = bt.x - m * scl.x;
    m = s.y * invN; vr = sq.y * invN - m * m; scl.y = gm.y * rsqrtf(vr + 1e-5f); sh.y = bt.y - m * scl.y;
    m = s.z * invN; vr = sq.z * invN - m * m; scl.z = gm.z * rsqrtf(vr + 1e-5f); sh.z = bt.z - m * scl.z;
    m = s.w * invN; vr = sq.w * invN - m * m; scl.w = gm.w * rsqrtf(vr + 1e-5f); sh.w = bt.w - m * scl.w;

    float4 acc = {0.f, 0.f, 0.f, 0.f};
    for (int n = beg + r; n < end; n += 8) {
        uint2 zp = ((const uint2*)z)[(size_t)n * 32 + q];
        acc.x += fmaxf(bfu_lo(zp.x) * scl.x + sh.x, 0.f);
        acc.y += fmaxf(bfu_hi(zp.x) * scl.y + sh.y, 0.f);
        acc.z += fmaxf(bfu_lo(zp.y) * scl.z + sh.z, 0.f);
        acc.w += fmaxf(bfu_hi(zp.y) * scl.w + sh.w, 0.f);
    }
    red[r][q * 4 + 0] = acc.x;
    red[r][q * 4 + 1] = acc.y;
    red[r][q * 4 + 2] = acc.z;
    red[r][q * 4 + 3] = acc.w;
    __syncthreads();
    if (t < 128) {
        float sm = 0.f;
        #pragma unroll
        for (int rr = 0; rr < 8; rr++) sm += red[rr][t];
        pool3[t] = sm;
    }
    __syncthreads();

    if (t < 64) {
        const int lane = t;
        const float* xr = pools + (size_t)g * (DIM * NLAYERS);
        float a[NCLASSES];
        #pragma unroll
        for (int o = 0; o < NCLASSES; o++) a[o] = 0.f;
        #pragma unroll
        for (int kk = 0; kk < DIM * NLAYERS; kk += 64) {
            float xv = (kk < 3 * DIM) ? xr[kk + lane] : pool3[kk - 3 * DIM + lane];
            const float* wrow = Wlin + (size_t)(kk + lane) * NCLASSES;
            #pragma unroll
            for (int o = 0; o < NCLASSES; o++) a[o] += xv * wrow[o];
        }
        #pragma unroll
        for (int o = 0; o < NCLASSES; o++) {
            float v = a[o];
            #pragma unroll
            for (int off = 32; off > 0; off >>= 1) v += __shfl_down(v, off, 64);
            if (lane == 0) out[(size_t)g * NCLASSES + o] = v + blin[o];
        }
    }
}

// ---------------------------------------------------------------------------
extern "C" void kernel_launch(void* const* d_in, const int* in_sizes, int n_in,
                              void* d_out, int out_size, void* d_ws, size_t ws_size,
                              hipStream_t stream)
{
    const float* x     = (const float*)d_in[0];
    const int*   src   = (const int*)d_in[1];
    const int*   dst   = ((const int*)d_in[1]) + N_EDGES;
    const int*   batch = (const int*)d_in[2];
    const float* W1    = (const float*)d_in[3];
    const float* b1    = (const float*)d_in[4];
    const float* W2    = (const float*)d_in[5];
    const float* b2    = (const float*)d_in[6];
    const float* eps   = (const float*)d_in[7];
    const float* gamma = (const float*)d_in[8];
    const float* beta  = (const float*)d_in[9];
    const float* Wlin  = (const float*)d_in[10];
    const float* blin  = (const float*)d_in[11];
    float* out = (float*)d_out;

    char* ws = (char*)d_ws;
    const size_t FEATH = (size_t)N_NODES * DIM * sizeof(unsigned short); // 12.8 MB
    size_t off = 0;
    unsigned int* buf_h = (unsigned int*)(ws + off); off += FEATH;       // bf16 h
    unsigned short* buf_z = (unsigned short*)(ws + off); off += FEATH;   // bf16 z
    float* pools  = (float*)(ws + off); off += (size_t)N_GRAPHS * DIM * NLAYERS * sizeof(float);
    float* stats  = (float*)(ws + off); off += (size_t)NLAYERS * 256 * sizeof(float);
    int*   deg4   = (int*)(ws + off);   off += (size_t)N_NODES * 4 * sizeof(int);  // also cursor4
    int*   rowptr4= (int*)(ws + off);   off += (size_t)(N_NODES * 4 + 1) * sizeof(int) + 12;
    int*   csr    = (int*)(ws + off);   off += (size_t)N_EDGES * sizeof(int);
    int*   gstart = (int*)(ws + off);   off += 2064;
    int*   bsum   = (int*)(ws + off);   off += 1024;
    unsigned short* whi = (unsigned short*)(ws + off); off += (size_t)NLAYERS * 2 * 16384 * 2;

    hipMemsetAsync(deg4, 0, (size_t)N_NODES * 4 * sizeof(int), stream);

    // ---- once per call: bucketed-CSR chain + fused prep ----
    hist_kernel<<<(N_EDGES + 255) / 256, 256, 0, stream>>>(src, dst, deg4);
    scan1_kernel<<<196, 256, 0, stream>>>(deg4, bsum);
    scan2_kernel<<<1, 256, 0, stream>>>(bsum);
    scan3_kernel<<<196, 256, 0, stream>>>(deg4, bsum, rowptr4, deg4 /*cursor4*/);
    fill_kernel<<<(N_EDGES + 255) / 256, 256, 0, stream>>>(src, dst, deg4, csr);
    prep_kernel<<<6959, 256, 0, stream>>>(batch, gstart, x, buf_h,
                                          W1, W2, whi, stats);

    for (int l = 0; l < NLAYERS; l++) {
        gin_layer_kernel<<<(N_NODES + 63) / 64, 256, 0, stream>>>(
            buf_h, rowptr4, csr, eps + l, buf_z,
            whi + (size_t)l * 32768,
            b1 + (size_t)l * DIM, b2 + (size_t)l * DIM,
            stats + (size_t)l * 256);
        if (l < NLAYERS - 1) {
            bnpool_kernel<<<N_GRAPHS, 256, 0, stream>>>(
                (const unsigned int*)buf_z, stats + (size_t)l * 256,
                gamma + (size_t)l * DIM, beta + (size_t)l * DIM,
                gstart, buf_h, pools, l);
        }
    }
    bnhead_kernel<<<N_GRAPHS, 256, 0, stream>>>(
        (const unsigned int*)buf_z, stats + (size_t)(NLAYERS - 1) * 256,
        gamma + (size_t)(NLAYERS - 1) * DIM, beta + (size_t)(NLAYERS - 1) * DIM,
        gstart, pools, Wlin, blin, out);
}

// Round 14
// 392.025 us; speedup vs baseline: 1.9362x; 1.0196x over previous
//
#include <hip/hip_runtime.h>

#define N_NODES 50000
#define N_EDGES 600000
#define N_GRAPHS 512
#define DIM 128
#define NLAYERS 4
#define NCLASSES 10
#define KPS 136      // padded LDS row stride in USHORTS (272 B, 16B-aligned)
#define NBUCK 4
#define BUCKSZ 12500 // source-node bucket size: 12500 rows * 256 B = 3.2 MB

typedef __attribute__((ext_vector_type(8))) short short8;
typedef __attribute__((ext_vector_type(4))) float f32x4;

union Frag { short8 s; uint4 u; };

// ---- fp32 <-> bf16 (RNE) helpers ----
__device__ inline unsigned short f2bf(float v) {
    union { float f; unsigned u; } c; c.f = v;
    unsigned u = c.u;
    u += 0x7FFFu + ((u >> 16) & 1u);
    return (unsigned short)(u >> 16);
}
__device__ inline float bfu_lo(unsigned u) {
    union { float f; unsigned x; } c; c.x = u << 16; return c.f;
}
__device__ inline float bfu_hi(unsigned u) {
    union { float f; unsigned x; } c; c.x = u & 0xFFFF0000u; return c.f;
}
__device__ inline void addRow(float* acc, const uint4& v) {
    acc[0] += bfu_lo(v.x); acc[1] += bfu_hi(v.x);
    acc[2] += bfu_lo(v.y); acc[3] += bfu_hi(v.y);
    acc[4] += bfu_lo(v.z); acc[5] += bfu_hi(v.z);
    acc[6] += bfu_lo(v.w); acc[7] += bfu_hi(v.w);
}

// ---------------------------------------------------------------------------
// scan1: per-block sums of deg4 (196 blocks x 256 int4)
// ---------------------------------------------------------------------------
__global__ __launch_bounds__(256) void scan1_kernel(
    const int* __restrict__ deg4, int* __restrict__ bsum)
{
    __shared__ int red[256];
    int t = threadIdx.x;
    int i4 = blockIdx.x * 256 + t;
    int s = 0;
    if (i4 < 50000) {
        int4 v = ((const int4*)deg4)[i4];
        s = v.x + v.y + v.z + v.w;
    }
    red[t] = s;
    __syncthreads();
    for (int off = 128; off > 0; off >>= 1) {
        if (t < off) red[t] += red[t + off];
        __syncthreads();
    }
    if (t == 0) bsum[blockIdx.x] = red[0];
}

// ---------------------------------------------------------------------------
// scan3 (fused with scan2): each block computes its own exclusive prefix of
// the 196 raw block sums (hot in L2), then the intra-block exclusive scan,
// writing rowptr4 + cursor4.  Eliminates the scan2 dispatch.
// ---------------------------------------------------------------------------
__global__ __launch_bounds__(256) void scan3_kernel(
    const int* __restrict__ deg4, const int* __restrict__ bsum,
    int* __restrict__ rowptr4, int* __restrict__ cursor4)
{
    __shared__ int red[256];
    __shared__ int bpf;
    int t = threadIdx.x;

    // ---- exclusive prefix of bsum over blocks < blockIdx.x ----
    int v0 = (t < 196 && t < (int)blockIdx.x) ? bsum[t] : 0;
    red[t] = v0;
    __syncthreads();
    for (int off = 128; off > 0; off >>= 1) {
        if (t < off) red[t] += red[t + off];
        __syncthreads();
    }
    if (t == 0) bpf = red[0];
    __syncthreads();
    const int prefix = bpf;

    // ---- intra-block scan (Hillis-Steele), as before ----
    int i4 = blockIdx.x * 256 + t;
    int4 v = {0, 0, 0, 0};
    if (i4 < 50000) v = ((const int4*)deg4)[i4];
    int s = v.x + v.y + v.z + v.w;
    __syncthreads();
    red[t] = s;
    __syncthreads();
    for (int off = 1; off < 256; off <<= 1) {
        int val = (t >= off) ? red[t - off] : 0;
        __syncthreads();
        red[t] += val;
        __syncthreads();
    }
    int run = prefix + (t ? red[t - 1] : 0);
    if (i4 < 50000) {
        int4 rp;
        rp.x = run; run += v.x;
        rp.y = run; run += v.y;
        rp.z = run; run += v.z;
        rp.w = run; run += v.w;
        ((int4*)rowptr4)[i4] = rp;
        ((int4*)cursor4)[i4] = rp;
    }
    if (blockIdx.x == 0 && t == 0) rowptr4[4 * N_NODES] = N_EDGES;
}

__global__ __launch_bounds__(256) void fill_kernel(
    const int* __restrict__ src, const int* __restrict__ dst,
    int* __restrict__ cursor4, int* __restrict__ csr)
{
    int e = blockIdx.x * 256 + threadIdx.x;
    if (e >= N_EDGES) return;
    int s = src[e];
    int p = atomicAdd(&cursor4[dst[e] * 4 + s / BUCKSZ], 1);
    csr[p] = s;
}

// ---------------------------------------------------------------------------
// Fused prep: graph bounds + x->bf16 + W pre-swizzle + stats zero + HIST
// (bucketed degree histogram folded in as an extra block range).
// Ranges: [0,196) bounds | [196,6446) xconv | [6446,6958) wconv |
// 6958 stats | [6959,9303) hist (600064 edge slots).
// ---------------------------------------------------------------------------
__global__ __launch_bounds__(256) void prep_kernel(
    const int* __restrict__ batch, int* __restrict__ gstart,
    const float* __restrict__ x, unsigned int* __restrict__ xb,
    const float* __restrict__ W1, const float* __restrict__ W2,
    unsigned short* __restrict__ whi, float* __restrict__ stats,
    const int* __restrict__ src, const int* __restrict__ dst,
    int* __restrict__ deg4)
{
    int b = blockIdx.x;
    int t = threadIdx.x;
    if (b < 196) {
        int n = b * 256 + t;
        if (n >= N_NODES) return;
        int bb = batch[n];
        int bp = (n == 0) ? -1 : batch[n - 1];
        for (int g = bp + 1; g <= bb; g++) gstart[g] = n;
        if (n == N_NODES - 1)
            for (int g = bb + 1; g <= N_GRAPHS; g++) gstart[g] = N_NODES;
    } else if (b < 6446) {
        int idx = (b - 196) * 256 + t;
        if (idx >= N_NODES * 32) return;
        float4 v = ((const float4*)x)[idx];
        uint2 o;
        o.x = (unsigned)f2bf(v.x) | ((unsigned)f2bf(v.y) << 16);
        o.y = (unsigned)f2bf(v.z) | ((unsigned)f2bf(v.w) << 16);
        ((uint2*)xb)[idx] = o;
    } else if (b < 6958) {
        int idx = (b - 6446) * 256 + t;     // < 131072 exactly
        int f   = idx & 16383;
        int w01 = (idx >> 14) & 1;
        int l   = idx >> 15;
        int j    = f & 7;
        int lane = (f >> 3) & 63;
        int cg   = (f >> 9) & 7;
        int ks   = f >> 12;
        int k = ks * 32 + (lane >> 4) * 8 + j;
        int n = cg * 16 + (lane & 15);
        const float* W = (w01 == 0 ? W1 : W2) + (size_t)l * 16384;
        whi[idx] = f2bf(W[k * 128 + n]);
    } else if (b == 6958) {
        #pragma unroll
        for (int i = 0; i < 4; i++) stats[i * 256 + t] = 0.f;
    } else {
        int e = (b - 6959) * 256 + t;
        if (e >= N_EDGES) return;
        int s = src[e];
        atomicAdd(&deg4[dst[e] * 4 + s / BUCKSZ], 1);
    }
}

// ---------------------------------------------------------------------------
// FUSED GIN layer (R13-measured version, byte-identical gather ladder).
// ---------------------------------------------------------------------------
__global__ __launch_bounds__(256) void gin_layer_kernel(
    const unsigned int* __restrict__ hb,
    const int* __restrict__ rowptr4, const int* __restrict__ csr,
    const float* __restrict__ epsP,
    unsigned short* __restrict__ z,
    const unsigned short* __restrict__ whi,
    const float* __restrict__ b1, const float* __restrict__ b2,
    float* __restrict__ stats)
{
    __shared__ unsigned short tpk[64 * KPS];   // 17408 B
    __shared__ float sums[1024];
    __shared__ float sqs[1024];

    const int t = threadIdx.x;
    const int lane = t & 63;
    const int w = t >> 6;
    const int wr = w & 1, wc = w >> 1;
    const int l15 = lane & 15, quad = lane >> 4;
    const int base = blockIdx.x * 64;

    // ---------------- Phase A: fused pull-aggregation ----------------
    {
        const int m = t >> 2;
        const int c = t & 3;
        const int n = base + m;
        const uint4* hb4 = (const uint4*)hb;
        float acc[32];
        #pragma unroll
        for (int i = 0; i < 32; i++) acc[i] = 0.f;
        if (n < N_NODES) {
            const float e1 = 1.0f + epsP[0];
            const uint4* self = hb4 + (size_t)n * 16 + c;
            #pragma unroll
            for (int j = 0; j < 4; j++) {
                uint4 v = self[j * 4];
                float* a = acc + j * 8;
                a[0] = e1 * bfu_lo(v.x); a[1] = e1 * bfu_hi(v.x);
                a[2] = e1 * bfu_lo(v.y); a[3] = e1 * bfu_hi(v.y);
                a[4] = e1 * bfu_lo(v.z); a[5] = e1 * bfu_hi(v.z);
                a[6] = e1 * bfu_lo(v.w); a[7] = e1 * bfu_hi(v.w);
            }
            int beg = rowptr4[n * 4], end = rowptr4[n * 4 + 4];
            int e = beg;
            if (e + 3 < end) {
                int s0 = csr[e], s1 = csr[e + 1], s2 = csr[e + 2], s3 = csr[e + 3];
                while (true) {
                    const uint4* r0 = hb4 + (size_t)s0 * 16 + c;
                    const uint4* r1 = hb4 + (size_t)s1 * 16 + c;
                    const uint4* r2 = hb4 + (size_t)s2 * 16 + c;
                    const uint4* r3 = hb4 + (size_t)s3 * 16 + c;
                    uint4 v00 = r0[0], v01 = r0[4], v02 = r0[8], v03 = r0[12];
                    uint4 v10 = r1[0], v11 = r1[4], v12 = r1[8], v13 = r1[12];
                    uint4 v20 = r2[0], v21 = r2[4], v22 = r2[8], v23 = r2[12];
                    uint4 v30 = r3[0], v31 = r3[4], v32 = r3[8], v33 = r3[12];
                    int en = e + 4;
                    bool more = (en + 3 < end);
                    if (more) {
                        s0 = csr[en]; s1 = csr[en + 1];
                        s2 = csr[en + 2]; s3 = csr[en + 3];
                    }
                    addRow(acc + 0, v00); addRow(acc + 8, v01); addRow(acc + 16, v02); addRow(acc + 24, v03);
                    addRow(acc + 0, v10); addRow(acc + 8, v11); addRow(acc + 16, v12); addRow(acc + 24, v13);
                    addRow(acc + 0, v20); addRow(acc + 8, v21); addRow(acc + 16, v22); addRow(acc + 24, v23);
                    addRow(acc + 0, v30); addRow(acc + 8, v31); addRow(acc + 16, v32); addRow(acc + 24, v33);
                    e = en;
                    if (!more) break;
                }
            }
            for (; e < end; e++) {
                int s0 = csr[e];
                const uint4* r0 = hb4 + (size_t)s0 * 16 + c;
                uint4 a0 = r0[0], a1 = r0[4], a2 = r0[8], a3 = r0[12];
                addRow(acc + 0, a0);  addRow(acc + 8, a1);
                addRow(acc + 16, a2); addRow(acc + 24, a3);
            }
        }
        // pack bf16 into A-layout LDS; 4 x 16B stores
        #pragma unroll
        for (int j = 0; j < 4; j++) {
            union { short8 s; unsigned short u[8]; } pk;
            #pragma unroll
            for (int i = 0; i < 8; i++) pk.u[i] = f2bf(acc[j * 8 + i]);
            *((short8*)&tpk[m * KPS + j * 32 + c * 8]) = pk.s;
        }
    }
    __syncthreads();

    f32x4 acc[2][4];
    #pragma unroll
    for (int s = 0; s < 2; s++)
        #pragma unroll
        for (int i = 0; i < 4; i++) acc[s][i] = (f32x4){0.f, 0.f, 0.f, 0.f};

    const int arow0 = (32 * wr + l15) * KPS;
    const int arow1 = arow0 + 16 * KPS;

    // ================= GEMM1: z0 @ W1 (A from LDS, bf16) =================
    #pragma unroll
    for (int kh = 0; kh < 2; kh++) {
        Frag bf[2][4];
        short8 a0[2], a1[2];
        #pragma unroll
        for (int kk = 0; kk < 2; kk++) {
            int ks = kh * 2 + kk;
            #pragma unroll
            for (int i = 0; i < 4; i++) {
                size_t woff = (size_t)(((ks * 8 + wc * 4 + i) * 64 + lane) * 8);
                bf[kk][i].s = *((const short8*)&whi[woff]);
            }
            a0[kk] = *((const short8*)&tpk[arow0 + ks * 32 + quad * 8]);
            a1[kk] = *((const short8*)&tpk[arow1 + ks * 32 + quad * 8]);
        }
        #pragma unroll
        for (int kk = 0; kk < 2; kk++) {
            #pragma unroll
            for (int i = 0; i < 4; i++) {
                acc[0][i] = __builtin_amdgcn_mfma_f32_16x16x32_bf16(a0[kk], bf[kk][i].s, acc[0][i], 0, 0, 0);
                acc[1][i] = __builtin_amdgcn_mfma_f32_16x16x32_bf16(a1[kk], bf[kk][i].s, acc[1][i], 0, 0, 0);
            }
        }
    }
    __syncthreads();

    // ---- bias + relu -> t (bf16) in LDS ----
    #pragma unroll
    for (int i = 0; i < 4; i++) {
        int col = wc * 64 + i * 16 + l15;
        float bb = b1[col];
        #pragma unroll
        for (int s = 0; s < 2; s++) {
            #pragma unroll
            for (int r = 0; r < 4; r++) {
                int m = 32 * wr + 16 * s + quad * 4 + r;
                float v = fmaxf(acc[s][i][r] + bb, 0.f);
                tpk[m * KPS + col] = f2bf(v);
            }
            acc[s][i] = (f32x4){0.f, 0.f, 0.f, 0.f};
        }
    }
    __syncthreads();

    // ================= GEMM2: t @ W2 =================
    const unsigned short* w2 = whi + 16384;
    #pragma unroll
    for (int kh = 0; kh < 2; kh++) {
        Frag bf[2][4];
        short8 a0[2], a1[2];
        #pragma unroll
        for (int kk = 0; kk < 2; kk++) {
            int ks = kh * 2 + kk;
            #pragma unroll
            for (int i = 0; i < 4; i++) {
                size_t woff = (size_t)(((ks * 8 + wc * 4 + i) * 64 + lane) * 8);
                bf[kk][i].s = *((const short8*)&w2[woff]);
            }
            a0[kk] = *((const short8*)&tpk[arow0 + ks * 32 + quad * 8]);
            a1[kk] = *((const short8*)&tpk[arow1 + ks * 32 + quad * 8]);
        }
        #pragma unroll
        for (int kk = 0; kk < 2; kk++) {
            #pragma unroll
            for (int i = 0; i < 4; i++) {
                acc[0][i] = __builtin_amdgcn_mfma_f32_16x16x32_bf16(a0[kk], bf[kk][i].s, acc[0][i], 0, 0, 0);
                acc[1][i] = __builtin_amdgcn_mfma_f32_16x16x32_bf16(a1[kk], bf[kk][i].s, acc[1][i], 0, 0, 0);
            }
        }
    }
    __syncthreads();   // tpk free for z staging

    // ---- bias; z-bf16 tile + stats partials ----
    {
        float colsum[4], colsq[4];
        #pragma unroll
        for (int i = 0; i < 4; i++) {
            int col = wc * 64 + i * 16 + l15;
            float bb = b2[col];
            float su = 0.f, q2 = 0.f;
            #pragma unroll
            for (int s = 0; s < 2; s++) {
                #pragma unroll
                for (int r = 0; r < 4; r++) {
                    int m = 32 * wr + 16 * s + quad * 4 + r;
                    int n = base + m;
                    float v = acc[s][i][r] + bb;
                    tpk[m * KPS + col] = f2bf(v);
                    if (n < N_NODES) { su += v; q2 += v * v; }
                }
            }
            colsum[i] = su; colsq[i] = q2;
        }
        #pragma unroll
        for (int i = 0; i < 4; i++) {
            sums[(w * 4 + i) * 64 + lane] = colsum[i];
            sqs [(w * 4 + i) * 64 + lane] = colsq[i];
        }
    }
    __syncthreads();

    // ---- coalesced z store (interleaved: contiguous 64B per 4-lane group) ----
    {
        int m2 = t >> 2, c2 = t & 3;
        int n2 = base + m2;
        if (n2 < N_NODES) {
            const uint4* srcp = (const uint4*)(tpk + m2 * KPS);
            uint4* dstp = (uint4*)z + (size_t)n2 * 16;
            #pragma unroll
            for (int j = 0; j < 4; j++) dstp[j * 4 + c2] = srcp[j * 4 + c2];
        }
    }
    if (t < 128) {
        int c = t;
        int wcc = c >> 6, ci = (c >> 4) & 3, cl = c & 15;
        float s = 0.f, q2 = 0.f;
        #pragma unroll
        for (int wrr = 0; wrr < 2; wrr++) {
            int ww = wcc * 2 + wrr;
            #pragma unroll
            for (int u = 0; u < 4; u++) {
                int ln = cl + u * 16;
                s  += sums[(ww * 4 + ci) * 64 + ln];
                q2 += sqs [(ww * 4 + ci) * 64 + ln];
            }
        }
        unsafeAtomicAdd(&stats[c], s);
        unsafeAtomicAdd(&stats[128 + c], q2);
    }
}

// ---------------------------------------------------------------------------
// BN apply + ReLU + write h (bf16) + pool; z packed bf16.  Layers 0..2.
// ---------------------------------------------------------------------------
__global__ __launch_bounds__(256) void bnpool_kernel(
    const unsigned int* __restrict__ z, const float* __restrict__ stats,
    const float* __restrict__ gamma, const float* __restrict__ beta,
    const int* __restrict__ gstart, unsigned int* __restrict__ hout,
    float* __restrict__ pools, int layer)
{
    __shared__ float red[8][128];
    const int g = blockIdx.x;
    const int t = threadIdx.x;
    const int q = t & 31, r = t >> 5;
    const int beg = gstart[g], end = gstart[g + 1];

    float4 s  = ((const float4*)stats)[q];
    float4 sq = ((const float4*)stats)[32 + q];
    float4 gm = ((const float4*)gamma)[q];
    float4 bt = ((const float4*)beta)[q];
    const float invN = 1.0f / (float)N_NODES;
    float m, vr;
    float4 scl, sh;
    m = s.x * invN; vr = sq.x * invN - m * m; scl.x = gm.x * rsqrtf(vr + 1e-5f); sh.x = bt.x - m * scl.x;
    m = s.y * invN; vr = sq.y * invN - m * m; scl.y = gm.y * rsqrtf(vr + 1e-5f); sh.y = bt.y - m * scl.y;
    m = s.z * invN; vr = sq.z * invN - m * m; scl.z = gm.z * rsqrtf(vr + 1e-5f); sh.z = bt.z - m * scl.z;
    m = s.w * invN; vr = sq.w * invN - m * m; scl.w = gm.w * rsqrtf(vr + 1e-5f); sh.w = bt.w - m * scl.w;

    float4 acc = {0.f, 0.f, 0.f, 0.f};
    for (int n = beg + r; n < end; n += 8) {
        uint2 zp = ((const uint2*)z)[(size_t)n * 32 + q];
        float4 hv;
        hv.x = fmaxf(bfu_lo(zp.x) * scl.x + sh.x, 0.f);
        hv.y = fmaxf(bfu_hi(zp.x) * scl.y + sh.y, 0.f);
        hv.z = fmaxf(bfu_lo(zp.y) * scl.z + sh.z, 0.f);
        hv.w = fmaxf(bfu_hi(zp.y) * scl.w + sh.w, 0.f);
        uint2 p;
        p.x = (unsigned)f2bf(hv.x) | ((unsigned)f2bf(hv.y) << 16);
        p.y = (unsigned)f2bf(hv.z) | ((unsigned)f2bf(hv.w) << 16);
        ((uint2*)hout)[(size_t)n * 32 + q] = p;
        acc.x += hv.x; acc.y += hv.y; acc.z += hv.z; acc.w += hv.w;
    }
    red[r][q * 4 + 0] = acc.x;
    red[r][q * 4 + 1] = acc.y;
    red[r][q * 4 + 2] = acc.z;
    red[r][q * 4 + 3] = acc.w;
    __syncthreads();
    if (t < 128) {
        float sm = 0.f;
        #pragma unroll
        for (int rr = 0; rr < 8; rr++) sm += red[rr][t];
        pools[(size_t)g * (DIM * NLAYERS) + (size_t)layer * DIM + t] = sm;
    }
}

// ---------------------------------------------------------------------------
// Layer-3 BN + ReLU + pool fused with the linear head (no h write needed).
// ---------------------------------------------------------------------------
__global__ __launch_bounds__(256) void bnhead_kernel(
    const unsigned int* __restrict__ z, const float* __restrict__ stats,
    const float* __restrict__ gamma, const float* __restrict__ beta,
    const int* __restrict__ gstart, const float* __restrict__ pools,
    const float* __restrict__ Wlin, const float* __restrict__ blin,
    float* __restrict__ out)
{
    __shared__ float red[8][128];
    __shared__ float pool3[128];
    const int g = blockIdx.x;
    const int t = threadIdx.x;
    const int q = t & 31, r = t >> 5;
    const int beg = gstart[g], end = gstart[g + 1];

    float4 s  = ((const float4*)stats)[q];
    float4 sq = ((const float4*)stats)[32 + q];
    float4 gm = ((const float4*)gamma)[q];
    float4 bt = ((const float4*)beta)[q];
    const float invN = 1.0f / (float)N_NODES;
    float m, vr;
    float4 scl, sh;
    m = s.x * invN; vr = sq.x * invN - m * m; scl.x = gm.x * rsqrtf(vr + 1e-5f); sh.x = bt.x - m * scl.x;
    m = s.y * invN; vr = sq.y * invN - m * m; scl.y = gm.y * rsqrtf(vr + 1e-5f); sh.y = bt.y - m * scl.y;
    m = s.z * invN; vr = sq.z * invN - m * m; scl.z = gm.z * rsqrtf(vr + 1e-5f); sh.z = bt.z - m * scl.z;
    m = s.w * invN; vr = sq.w * invN - m * m; scl.w = gm.w * rsqrtf(vr + 1e-5f); sh.w = bt.w - m * scl.w;

    float4 acc = {0.f, 0.f, 0.f, 0.f};
    for (int n = beg + r; n < end; n += 8) {
        uint2 zp = ((const uint2*)z)[(size_t)n * 32 + q];
        acc.x += fmaxf(bfu_lo(zp.x) * scl.x + sh.x, 0.f);
        acc.y += fmaxf(bfu_hi(zp.x) * scl.y + sh.y, 0.f);
        acc.z += fmaxf(bfu_lo(zp.y) * scl.z + sh.z, 0.f);
        acc.w += fmaxf(bfu_hi(zp.y) * scl.w + sh.w, 0.f);
    }
    red[r][q * 4 + 0] = acc.x;
    red[r][q * 4 + 1] = acc.y;
    red[r][q * 4 + 2] = acc.z;
    red[r][q * 4 + 3] = acc.w;
    __syncthreads();
    if (t < 128) {
        float sm = 0.f;
        #pragma unroll
        for (int rr = 0; rr < 8; rr++) sm += red[rr][t];
        pool3[t] = sm;
    }
    __syncthreads();

    if (t < 64) {
        const int lane = t;
        const float* xr = pools + (size_t)g * (DIM * NLAYERS);
        float a[NCLASSES];
        #pragma unroll
        for (int o = 0; o < NCLASSES; o++) a[o] = 0.f;
        #pragma unroll
        for (int kk = 0; kk < DIM * NLAYERS; kk += 64) {
            float xv = (kk < 3 * DIM) ? xr[kk + lane] : pool3[kk - 3 * DIM + lane];
            const float* wrow = Wlin + (size_t)(kk + lane) * NCLASSES;
            #pragma unroll
            for (int o = 0; o < NCLASSES; o++) a[o] += xv * wrow[o];
        }
        #pragma unroll
        for (int o = 0; o < NCLASSES; o++) {
            float v = a[o];
            #pragma unroll
            for (int off = 32; off > 0; off >>= 1) v += __shfl_down(v, off, 64);
            if (lane == 0) out[(size_t)g * NCLASSES + o] = v + blin[o];
        }
    }
}

// ---------------------------------------------------------------------------
extern "C" void kernel_launch(void* const* d_in, const int* in_sizes, int n_in,
                              void* d_out, int out_size, void* d_ws, size_t ws_size,
                              hipStream_t stream)
{
    const float* x     = (const float*)d_in[0];
    const int*   src   = (const int*)d_in[1];
    const int*   dst   = ((const int*)d_in[1]) + N_EDGES;
    const int*   batch = (const int*)d_in[2];
    const float* W1    = (const float*)d_in[3];
    const float* b1    = (const float*)d_in[4];
    const float* W2    = (const float*)d_in[5];
    const float* b2    = (const float*)d_in[6];
    const float* eps   = (const float*)d_in[7];
    const float* gamma = (const float*)d_in[8];
    const float* beta  = (const float*)d_in[9];
    const float* Wlin  = (const float*)d_in[10];
    const float* blin  = (const float*)d_in[11];
    float* out = (float*)d_out;

    char* ws = (char*)d_ws;
    const size_t FEATH = (size_t)N_NODES * DIM * sizeof(unsigned short); // 12.8 MB
    size_t off = 0;
    unsigned int* buf_h = (unsigned int*)(ws + off); off += FEATH;       // bf16 h
    unsigned short* buf_z = (unsigned short*)(ws + off); off += FEATH;   // bf16 z
    float* pools  = (float*)(ws + off); off += (size_t)N_GRAPHS * DIM * NLAYERS * sizeof(float);
    float* stats  = (float*)(ws + off); off += (size_t)NLAYERS * 256 * sizeof(float);
    int*   deg4   = (int*)(ws + off);   off += (size_t)N_NODES * 4 * sizeof(int);  // also cursor4
    int*   rowptr4= (int*)(ws + off);   off += (size_t)(N_NODES * 4 + 1) * sizeof(int) + 12;
    int*   csr    = (int*)(ws + off);   off += (size_t)N_EDGES * sizeof(int);
    int*   gstart = (int*)(ws + off);   off += 2064;
    int*   bsum   = (int*)(ws + off);   off += 1024;
    unsigned short* whi = (unsigned short*)(ws + off); off += (size_t)NLAYERS * 2 * 16384 * 2;

    hipMemsetAsync(deg4, 0, (size_t)N_NODES * 4 * sizeof(int), stream);

    // ---- once per call: fused prep(+hist) + 2-kernel scan + fill ----
    prep_kernel<<<9303, 256, 0, stream>>>(batch, gstart, x, buf_h,
                                          W1, W2, whi, stats,
                                          src, dst, deg4);
    scan1_kernel<<<196, 256, 0, stream>>>(deg4, bsum);
    scan3_kernel<<<196, 256, 0, stream>>>(deg4, bsum, rowptr4, deg4 /*cursor4*/);
    fill_kernel<<<(N_EDGES + 255) / 256, 256, 0, stream>>>(src, dst, deg4, csr);

    for (int l = 0; l < NLAYERS; l++) {
        gin_layer_kernel<<<(N_NODES + 63) / 64, 256, 0, stream>>>(
            buf_h, rowptr4, csr, eps + l, buf_z,
            whi + (size_t)l * 32768,
            b1 + (size_t)l * DIM, b2 + (size_t)l * DIM,
            stats + (size_t)l * 256);
        if (l < NLAYERS - 1) {
            bnpool_kernel<<<N_GRAPHS, 256, 0, stream>>>(
                (const unsigned int*)buf_z, stats + (size_t)l * 256,
                gamma + (size_t)l * DIM, beta + (size_t)l * DIM,
                gstart, buf_h, pools, l);
        }
    }
    bnhead_kernel<<<N_GRAPHS, 256, 0, stream>>>(
        (const unsigned int*)buf_z, stats + (size_t)(NLAYERS - 1) * 256,
        gamma + (size_t)(NLAYERS - 1) * DIM, beta + (size_t)(NLAYERS - 1) * DIM,
        gstart, pools, Wlin, blin, out);
}